// Round 3
// baseline (788.919 us; speedup 1.0000x reference)
//
#include <hip/hip_runtime.h>

typedef unsigned short bfu;                                     // bf16 storage
typedef __attribute__((ext_vector_type(8))) __bf16 bf16x8;      // MFMA A/B frag
typedef __attribute__((ext_vector_type(4))) float f32x4;        // MFMA C/D frag

__device__ __forceinline__ float bf2f(bfu u) {
    unsigned int x = ((unsigned int)u) << 16;
    return __builtin_bit_cast(float, x);
}
__device__ __forceinline__ bfu f2bf(float f) {  // round-nearest-even
    unsigned int u = __builtin_bit_cast(unsigned int, f);
    unsigned int r = (u + 0x7fffu + ((u >> 16) & 1u)) >> 16;
    return (bfu)r;
}
__device__ __forceinline__ float sigm(float x) { return 1.0f / (1.0f + __expf(-x)); }
// fast tanh-GELU (~1e-3 abs err) for sigmoid-smooth heads
__device__ __forceinline__ float gelu_f(float x) {
    const float y = 0.7978845608f * (x + 0.044715f * x * x * x);
    const float t = 1.f - 2.f / (__expf(2.f * y) + 1.f);
    return 0.5f * x * (1.f + t);
}
// exact erf GELU: info head only (round(sig*10) histogram is discontinuous)
__device__ __forceinline__ float gelu_x(float x) {
    return 0.5f * x * (1.0f + erff(x * 0.70710678118654752f));
}

// async global->LDS, 16B/lane; LDS dest = wave-uniform base + lane*16.
__device__ __forceinline__ void async16(const void* g, void* l) {
    __builtin_amdgcn_global_load_lds((const __attribute__((address_space(1))) void*)g,
                                     (__attribute__((address_space(3))) void*)l, 16, 0, 0);
}

// ---------------------------------------------------------------- transpose
struct TDesc { const float* src; bfu* dst; int K, N, blk0; };
struct TPack { TDesc d[9]; };

__global__ __launch_bounds__(256) void transpose_k(TPack p) {
    const int bid = blockIdx.x;
    int j = 0;
#pragma unroll
    for (int i = 1; i < 9; ++i)
        if (bid >= p.d[i].blk0) j = i;
    const TDesc d = p.d[j];
    const int local = bid - d.blk0;
    const int tkn = d.K >> 6;
    const int tk = local % tkn, tn = local / tkn;
    const int k0 = tk * 64, n0 = tn * 64;
    __shared__ float tile[64][65];
    const int tx = threadIdx.x & 63, ty = threadIdx.x >> 6;
#pragma unroll
    for (int i = 0; i < 16; ++i) {
        const int r = ty * 16 + i;
        tile[r][tx] = d.src[(size_t)(k0 + r) * d.N + n0 + tx];
    }
    __syncthreads();
#pragma unroll
    for (int i = 0; i < 16; ++i) {
        const int n = ty * 16 + i;
        d.dst[(size_t)(n0 + n) * d.K + k0 + tx] = f2bf(tile[tx][n]);
    }
}

// --------------------------- prep: zero accumulators + build padded disc-l2
__global__ __launch_bounds__(256)
void prep_k(float* accz, int nacc, bfu* disc2pad, const float* w3,
            const float* b2, float* w3pad, float* b2pad) {
    const int i = blockIdx.x * 256 + threadIdx.x;
    if (i < nacc) accz[i] = 0.f;
    if (i < 64 * 256) disc2pad[64 * 256 + i] = 0;     // zero pad rows 64..127
    if (i < 128) {
        w3pad[i] = (i < 64) ? w3[i] : 0.f;            // pad dot weights with 0
        b2pad[i] = (i < 64) ? b2[i] : 0.f;            // pad bias with 0
    }
}

// ------------------------------------------------------- geometric + cast
__global__ __launch_bounds__(256)
void geomcast_k(const float* F0, const float* F1, bfu* D0, bfu* D1,
                float* g0, float* g1, float* p0, float* p1) {
    const int z = blockIdx.y;
    const float* F = z ? F1 : F0;
    bfu* D = z ? D1 : D0;
    float* gout = z ? g1 : g0;
    float* part = z ? p1 : p0;
    const int wave = threadIdx.x >> 6, lane = threadIdx.x & 63;
    const int row = blockIdx.x * 4 + wave;
    const float* fr = F + (size_t)row * 768;
    bfu* dr = D + (size_t)row * 768;
    float sum = 0.f, ss = 0.f, cnt = 0.f;
#pragma unroll
    for (int i = 0; i < 3; ++i) {
        const float4 v = *(const float4*)(fr + i * 256 + lane * 4);
        sum += v.x + v.y + v.z + v.w;
        ss += v.x * v.x + v.y * v.y + v.z * v.z + v.w * v.w;
        cnt += ((fabsf(v.x) > 0.01f) ? 1.f : 0.f) + ((fabsf(v.y) > 0.01f) ? 1.f : 0.f) +
               ((fabsf(v.z) > 0.01f) ? 1.f : 0.f) + ((fabsf(v.w) > 0.01f) ? 1.f : 0.f);
        ushort4 b;
        b.x = f2bf(v.x); b.y = f2bf(v.y); b.z = f2bf(v.z); b.w = f2bf(v.w);
        *(ushort4*)(dr + i * 256 + lane * 4) = b;
    }
#pragma unroll
    for (int off = 32; off; off >>= 1) {
        sum += __shfl_xor(sum, off);
        ss  += __shfl_xor(ss, off);
        cnt += __shfl_xor(cnt, off);
    }
    if (lane == 0) {
        const float n = sqrtf(ss);
        const float nq = sigm((n - 1.f) * 2.f);
        const float sp = cnt * (1.f / 768.f);
        float var = (ss - sum * sum * (1.f / 768.f)) * (1.f / 767.f);
        var = fmaxf(var, 0.f);
        const float sq = sigm(sqrtf(var) * 10.f - 1.f);
        gout[row] = (nq + sp + sq) * (1.f / 3.f);
        if (part) {
            const float cq = (n > 0.01f) ? (1.f / 768.f) : 0.f;
            const float nc = fmaxf(n, 1e-12f);
            const float dq = sigm(ss / (nc * nc) - 0.5f);
            part[row] = (cq + dq) * (1.f / 3.f);
        }
    }
}

// ------------------------------------------------------------------- GEMM
// R7: 256x256 block, 8 waves (2x4), wave tile 128x64 (MT=8,NT=4), BK=64,
// 128 KiB LDS (2 slots A + 2 slots W, 256x64 each), 4-phase interleave with
// counted vmcnt (T3+T4) + setprio (T5). Rationale: R6 proved the 2-barrier
// 128x128 structure is NOT load-latency-bound; it is LDS-traffic/structure
// bound (wave AI only 32 FLOP/B of LDS). The 128x64 wave tile cuts LDS reads
// per FLOP 25% and the phase-split lets ds_read / stage / MFMA of different
// sub-steps overlap (m196: the fine interleave is the lever; m218: counted
// vmcnt vs drain-0 = +38-73%).
// Race-freedom: slot re-stage happens only in a phase strictly after (via a
// trailing barrier) the phase where every wave lgkm(0)-drained its last reads
// of that slot. Tile-kt data is gated by vmcnt(4) at iter kt-1's P3 (before
// the barrier), so all waves' tile-kt loads landed before any P0 ds_read.
// Steady state: W of tile kt+2 stays in flight across the gate (never 0).
// N per block = 256 -> segments fused in PAIRS of 128-col halves sharing A;
// odd counts use a skip-half (mode 3).
struct Half {
    const bfu* W;                    // this half's W rows [128][K]
    const float* bias;               // per-col bias (half-local, 128)
    const float* dotw;               // mode1: dot weights (half-local, 128)
    bfu* C;                          // mode0/2: store base (half-local cols)
    float* acc;                      // mode1: per-row fp32 accumulator
    int ldc, mode;                   // mode 3 = skip (garbage half)
};
struct Seg {
    const bfu* A; const bfu* A2;     // A2 supplies cols >= Ksplit (concat)
    Half h[2];
    int K, Ksplit, lda, Mtiles;      // Mtiles in 256-row units
};
struct SegPack { Seg s[7]; };

__global__ __launch_bounds__(512, 2)
void gemm_k(SegPack p) {
    constexpr int BK = 64;
    __shared__ bfu LDS[65536];                    // 128 KiB
    bfu* As0 = LDS;                               // 256x64 = 32 KB
    bfu* As1 = LDS + 16384;
    bfu* Ws0 = LDS + 32768;                       // rows 0-127 = h0, 128-255 = h1
    bfu* Ws1 = LDS + 49152;

    const int NTt = gridDim.x;
    const int g = blockIdx.y * NTt + blockIdx.x;
    const int G8 = NTt * 8;                       // gridDim.y % 8 == 0 always
    const int m = (g / G8) * 8 + (g & 7);
    const int n = (g % G8) >> 3;
    const Seg sg = p.s[n];
    if (m >= sg.Mtiles) return;                   // uniform early-exit
    const int t = threadIdx.x;
    const int wave = t >> 6, lane = t & 63;
    const int row_l = lane & 15, kq = lane >> 4;
    const int m0 = m * 256;
    const int wm = wave >> 2;                     // 0..1 -> rows wm*128
    const int wn = wave & 3;                      // 0..3 -> cols wn*64
    const int half = wn >> 1;                     // which 128-col half

    // staging: thread t stages 16B chunk (t&7) of rows r0+64i (XOR-swizzled
    // source chunk; r&7 invariant since rows step by 64)
    const int r0 = t >> 3;
    const int cc = ((t & 7) ^ (r0 & 7)) << 3;
    const bfu* pA[4];
    const bfu* pW[4];
#pragma unroll
    for (int i = 0; i < 4; ++i)
        pA[i] = sg.A + (size_t)(m0 + r0 + 64 * i) * sg.lda + cc;
#pragma unroll
    for (int i = 0; i < 2; ++i) {
        pW[i]     = sg.h[0].W + (size_t)(r0 + 64 * i) * sg.K + cc;
        pW[2 + i] = sg.h[1].W + (size_t)(r0 + 64 * i) * sg.K + cc;
    }
    const int nkt = sg.K >> 6;                    // even: 4 / 12 / 24
    const int ktsw = (sg.Ksplit < sg.K) ? (sg.Ksplit >> 6) : 0x7fffffff;

    f32x4 acc[8][4] = {};

    auto stageA = [&](int sn, bfu* Ad) {
        if (sn == ktsw) {                         // concat boundary: switch A
#pragma unroll
            for (int i = 0; i < 4; ++i)
                pA[i] = sg.A2 + (size_t)(m0 + r0 + 64 * i) * sg.lda + cc;
        }
#pragma unroll
        for (int i = 0; i < 4; ++i)
            async16(pA[i], Ad + ((i * 512 + wave * 64) << 3));
#pragma unroll
        for (int i = 0; i < 4; ++i) pA[i] += BK;
    };
    auto ldF = [&](const bfu* base, int row, int ks) -> bf16x8 {
        return *(const bf16x8*)(base + row * BK + (((ks * 4 + kq) ^ (row & 7)) << 3));
    };

    // ---- prologue: W t0 -> Ws0, A t0 -> As0, W t1 -> Ws1 (12 loads) ----
#pragma unroll
    for (int i = 0; i < 4; ++i)
        async16(pW[i], Ws0 + ((i * 512 + wave * 64) << 3));
#pragma unroll
    for (int i = 0; i < 4; ++i) pW[i] += BK;
    stageA(0, As0);
#pragma unroll
    for (int i = 0; i < 4; ++i)
        async16(pW[i], Ws1 + ((i * 512 + wave * 64) << 3));
#pragma unroll
    for (int i = 0; i < 4; ++i) pW[i] += BK;
    asm volatile("s_waitcnt vmcnt(4)" ::: "memory");   // drain W t0 + A t0
    __builtin_amdgcn_s_barrier();

    auto do_iter = [&](bfu* Acur, bfu* Aoth, bfu* Wcur, int kt) {
        bf16x8 af[4], b0[4], b1[4];
        // ---------------- P0: af(g0,ks0) + both bf; stage A(kt+1) ----------
#pragma unroll
        for (int q = 0; q < 4; ++q)
            af[q] = ldF(Acur, wm * 128 + q * 16 + row_l, 0);
#pragma unroll
        for (int ni = 0; ni < 4; ++ni) {
            const int rB = wn * 64 + ni * 16 + row_l;
            b0[ni] = ldF(Wcur, rB, 0);
            b1[ni] = ldF(Wcur, rB, 1);
        }
        if (kt + 1 < nkt) stageA(kt + 1, Aoth);
        __builtin_amdgcn_s_barrier();
        asm volatile("s_waitcnt lgkmcnt(0)" ::: "memory");
        __builtin_amdgcn_sched_barrier(0);
        __builtin_amdgcn_s_setprio(1);
#pragma unroll
        for (int q = 0; q < 4; ++q)
#pragma unroll
            for (int ni = 0; ni < 4; ++ni)
                acc[q][ni] = __builtin_amdgcn_mfma_f32_16x16x32_bf16(af[q], b0[ni], acc[q][ni], 0, 0, 0);
        __builtin_amdgcn_s_setprio(0);
        __builtin_amdgcn_s_barrier();
        // ---------------- P1: af(g0,ks1); stage W(kt+2) h0 -----------------
#pragma unroll
        for (int q = 0; q < 4; ++q)
            af[q] = ldF(Acur, wm * 128 + q * 16 + row_l, 1);
        if (kt + 2 < nkt) {
            async16(pW[0], Wcur + ((0 * 512 + wave * 64) << 3));
            async16(pW[1], Wcur + ((1 * 512 + wave * 64) << 3));
        }
        __builtin_amdgcn_s_barrier();
        asm volatile("s_waitcnt lgkmcnt(0)" ::: "memory");
        __builtin_amdgcn_sched_barrier(0);
        __builtin_amdgcn_s_setprio(1);
#pragma unroll
        for (int q = 0; q < 4; ++q)
#pragma unroll
            for (int ni = 0; ni < 4; ++ni)
                acc[q][ni] = __builtin_amdgcn_mfma_f32_16x16x32_bf16(af[q], b1[ni], acc[q][ni], 0, 0, 0);
        __builtin_amdgcn_s_setprio(0);
        __builtin_amdgcn_s_barrier();
        // ---------------- P2: af(g1,ks0); stage W(kt+2) h1 -----------------
#pragma unroll
        for (int q = 0; q < 4; ++q)
            af[q] = ldF(Acur, wm * 128 + 64 + q * 16 + row_l, 0);
        if (kt + 2 < nkt) {
            async16(pW[2], Wcur + ((2 * 512 + wave * 64) << 3));
            async16(pW[3], Wcur + ((3 * 512 + wave * 64) << 3));
#pragma unroll
            for (int i = 0; i < 4; ++i) pW[i] += BK;
        }
        __builtin_amdgcn_s_barrier();
        asm volatile("s_waitcnt lgkmcnt(0)" ::: "memory");
        __builtin_amdgcn_sched_barrier(0);
        __builtin_amdgcn_s_setprio(1);
#pragma unroll
        for (int q = 0; q < 4; ++q)
#pragma unroll
            for (int ni = 0; ni < 4; ++ni)
                acc[4 + q][ni] = __builtin_amdgcn_mfma_f32_16x16x32_bf16(af[q], b0[ni], acc[4 + q][ni], 0, 0, 0);
        __builtin_amdgcn_s_setprio(0);
        __builtin_amdgcn_s_barrier();
        // ---------------- P3: af(g1,ks1); counted gate for tile kt+1 -------
#pragma unroll
        for (int q = 0; q < 4; ++q)
            af[q] = ldF(Acur, wm * 128 + 64 + q * 16 + row_l, 1);
        if (kt + 2 < nkt) { asm volatile("s_waitcnt vmcnt(4)" ::: "memory"); }
        else              { asm volatile("s_waitcnt vmcnt(0)" ::: "memory"); }
        __builtin_amdgcn_s_barrier();
        asm volatile("s_waitcnt lgkmcnt(0)" ::: "memory");
        __builtin_amdgcn_sched_barrier(0);
        __builtin_amdgcn_s_setprio(1);
#pragma unroll
        for (int q = 0; q < 4; ++q)
#pragma unroll
            for (int ni = 0; ni < 4; ++ni)
                acc[4 + q][ni] = __builtin_amdgcn_mfma_f32_16x16x32_bf16(af[q], b1[ni], acc[4 + q][ni], 0, 0, 0);
        __builtin_amdgcn_s_setprio(0);
        __builtin_amdgcn_s_barrier();
    };

    for (int kt = 0; kt < nkt; kt += 2) {
        do_iter(As0, As1, Ws0, kt);
        do_iter(As1, As0, Ws1, kt + 1);
    }

    // ---- epilogue; C/D layout: col=lane&15, row=quad*4+reg (m89/m91) ----
    const Half hh = sg.h[half];
    if (hh.mode == 0) {
#pragma unroll
        for (int ni = 0; ni < 4; ++ni) {
            const int lcol = (wn & 1) * 64 + ni * 16 + row_l;
            const float bv = hh.bias[lcol];
#pragma unroll
            for (int mi = 0; mi < 8; ++mi)
#pragma unroll
                for (int r = 0; r < 4; ++r) {
                    const int row = m0 + wm * 128 + mi * 16 + kq * 4 + r;
                    hh.C[(size_t)row * hh.ldc + lcol] = f2bf(gelu_f(acc[mi][ni][r] + bv));
                }
        }
    } else if (hh.mode == 2) {
#pragma unroll
        for (int ni = 0; ni < 4; ++ni) {
            const int lcol = (wn & 1) * 64 + ni * 16 + row_l;
            const float bv = hh.bias[lcol];
#pragma unroll
            for (int mi = 0; mi < 8; ++mi)
#pragma unroll
                for (int r = 0; r < 4; ++r) {
                    const int row = m0 + wm * 128 + mi * 16 + kq * 4 + r;
                    hh.C[(size_t)row * hh.ldc + lcol] = f2bf(gelu_x(acc[mi][ni][r] + bv));
                }
        }
    } else if (hh.mode == 1) {
#pragma unroll
        for (int mi = 0; mi < 8; ++mi)
#pragma unroll
            for (int r = 0; r < 4; ++r) {
                float s = 0.f;
#pragma unroll
                for (int ni = 0; ni < 4; ++ni) {
                    const int lcol = (wn & 1) * 64 + ni * 16 + row_l;
                    s += hh.dotw[lcol] * gelu_f(acc[mi][ni][r] + hh.bias[lcol]);
                }
                s += __shfl_xor(s, 1); s += __shfl_xor(s, 2);
                s += __shfl_xor(s, 4); s += __shfl_xor(s, 8);
                if (row_l == 0)
                    atomicAdd(hh.acc + m0 + wm * 128 + mi * 16 + kq * 4 + r, s);
            }
    }
    // mode 3: skip half
}

// -------------------------------- BN=64 GEMM + fused entropy (info l2)
__global__ __launch_bounds__(256)
void gemm64ent_k(const bfu* __restrict__ A, const bfu* __restrict__ W,
                 const float* __restrict__ bias, const float* __restrict__ part,
                 float* out, int B, int K, int lda) {
    constexpr int BK = 64, MT = 2, NT = 4;
    __shared__ __align__(16) float smemf[12288];  // 48KB: dbuf staging | ET union
    bfu* As0 = (bfu*)smemf;                       // 128x64 bf16 = 16 KB
    bfu* Ws0 = (bfu*)smemf + 128 * BK;            // 64x64 bf16 = 8 KB
    bfu* As1 = (bfu*)smemf + 192 * BK;
    bfu* Ws1 = (bfu*)smemf + 320 * BK;
    float* ET = smemf;                            // 128 x 65 fp32 after K-loop
    const int t = threadIdx.x;
    const int wave = t >> 6, lane = t & 63;
    const int row_l = lane & 15, kq = lane >> 4;
    const int m0 = blockIdx.x * 128;
    const int wrow0 = wave * 32;
    f32x4 acc[MT][NT] = {};
    const int nkt = K / BK;

    const int r0 = t >> 3;
    const int cc = ((t & 7) ^ (r0 & 7)) << 3;
    const size_t strA = (size_t)32 * lda;
    const size_t strW = (size_t)32 * K;
    const bfu* pA[4];
    const bfu* pW[2];
#pragma unroll
    for (int i = 0; i < 4; ++i)
        pA[i] = A + (size_t)(m0 + r0) * lda + cc + i * strA;
#pragma unroll
    for (int i = 0; i < 2; ++i)
        pW[i] = W + (size_t)r0 * K + cc + i * strW;

    auto stage = [&](bfu* Ad, bfu* Wd) {
#pragma unroll
        for (int i = 0; i < 4; ++i)
            async16(pA[i], Ad + ((i * 256 + wave * 64) << 3));
#pragma unroll
        for (int i = 0; i < 2; ++i)
            async16(pW[i], Wd + ((i * 256 + wave * 64) << 3));
#pragma unroll
        for (int i = 0; i < 4; ++i) pA[i] += BK;
#pragma unroll
        for (int i = 0; i < 2; ++i) pW[i] += BK;
    };
    auto compute = [&](const bfu* Ab, const bfu* Wb) {
#pragma unroll
        for (int ks = 0; ks < 2; ++ks) {
            bf16x8 af[MT], bfr[NT];
#pragma unroll
            for (int mi = 0; mi < MT; ++mi) {
                const int rA = wrow0 + mi * 16 + row_l;
                af[mi] = *(const bf16x8*)(Ab + rA * BK + (((ks * 4 + kq) ^ (rA & 7)) << 3));
            }
#pragma unroll
            for (int ni = 0; ni < NT; ++ni) {
                const int rB = ni * 16 + row_l;
                bfr[ni] = *(const bf16x8*)(Wb + rB * BK + (((ks * 4 + kq) ^ (rB & 7)) << 3));
            }
#pragma unroll
            for (int mi = 0; mi < MT; ++mi)
#pragma unroll
                for (int ni = 0; ni < NT; ++ni)
                    acc[mi][ni] = __builtin_amdgcn_mfma_f32_16x16x32_bf16(af[mi], bfr[ni], acc[mi][ni], 0, 0, 0);
        }
    };

    stage(As0, Ws0);
    __syncthreads();
    for (int kt = 0; kt < nkt; kt += 2) {
        stage(As1, Ws1);
        compute(As0, Ws0);
        __syncthreads();
        if (kt + 2 < nkt) stage(As0, Ws0);
        compute(As1, Ws1);
        __syncthreads();
    }

    // dump 128x64 fp32 logits (no activation) to LDS
#pragma unroll
    for (int mi = 0; mi < MT; ++mi)
#pragma unroll
        for (int ni = 0; ni < NT; ++ni) {
            const int col = ni * 16 + row_l;
            const float bv = bias[col];
#pragma unroll
            for (int r = 0; r < 4; ++r)
                ET[(wrow0 + mi * 16 + kq * 4 + r) * 65 + col] = acc[mi][ni][r] + bv;
        }
    __syncthreads();
    if (t < 128) {   // one thread per row: histogram entropy over 64 logits
        int cnt[11];
#pragma unroll
        for (int b = 0; b < 11; ++b) cnt[b] = 0;
        for (int j = 0; j < 64; ++j) {
            const int d = (int)rintf(sigm(ET[t * 65 + j]) * 10.f);
#pragma unroll
            for (int b = 0; b < 11; ++b) cnt[b] += (d == b);
        }
        float ent = 0.f;
#pragma unroll
        for (int b = 0; b < 11; ++b) {
            if (cnt[b] > 0) {
                const float pp = (float)cnt[b] * (1.f / 64.f);
                ent -= pp * __logf(pp + 1e-8f);
            }
        }
        const int row = m0 + t;
        const int orow = (row < B) ? 4 : 5;
        const int rl = (row < B) ? row : row - B;
        out[(size_t)orow * B + rl] = part[row] + sigm(ent - 2.f) * (1.f / 3.f);
    }
}

// --------------- finalize: sigmoids over fused-dot accumulators + overall
__global__ __launch_bounds__(256)
void finalize_k(float* out, const float* a_imp1, const float* a_imp2,
                const float* a_co, const float* a_ce, const float* a_df,
                const float* a_d1, const float* a_d2,
                const float* imp_b2, const float* disc_b3,
                const float* cons_b3, const float* diff_b3, int B) {
    const int i = blockIdx.x * 256 + threadIdx.x;
    if (i >= B) return;
    const float ib = imp_b2[0], db = disc_b3[0], cb = cons_b3[0], fb = diff_b3[0];
    const float o6 = sigm(a_co[i] + cb);
    const float o7 = sigm(a_ce[i] + cb);
    const float o8 = sigm(a_imp1[i] + ib);
    const float o9 = sigm(a_imp1[B + i] + ib);
    out[6 * B + i] = o6;
    out[7 * B + i] = o7;
    out[8 * B + i] = o8;
    out[9 * B + i] = o9;
    out[10 * B + i] = sigm(a_imp2[i] + ib);
    out[11 * B + i] = sigm(a_imp2[B + i] + ib);
    out[12 * B + i] = sigm(a_d1[i] + db);
    out[14 * B + i] = sigm(a_d1[B + i] + db);
    out[13 * B + i] = sigm(a_d2[i] + db);
    out[15 * B + i] = sigm(a_d2[B + i] + db);
    out[16 * B + i] = sigm(a_df[i] + fb);
    const float v = out[0 * B + i] + out[1 * B + i] + out[4 * B + i] + out[5 * B + i] +
                    o7 + 0.5f * (o8 + o9);
    out[17 * B + i] = v * (1.f / 6.f);
}

extern "C" void kernel_launch(void* const* d_in, const int* in_sizes, int n_in,
                              void* d_out, int out_size, void* d_ws, size_t ws_size,
                              hipStream_t stream) {
    const int B = in_sizes[4];  // 16384
    const int B2 = 2 * B;
    float* out = (float*)d_out;
    const float* img  = (const float*)d_in[0];
    const float* txt  = (const float*)d_in[1];
    const float* eimg = (const float*)d_in[2];
    const float* etxt = (const float*)d_in[3];
    const float* info_w1 = (const float*)d_in[5];  const float* info_b1 = (const float*)d_in[6];
    const float* info_w2 = (const float*)d_in[7];  const float* info_b2 = (const float*)d_in[8];
    const float* imp_w1  = (const float*)d_in[9];  const float* imp_b1  = (const float*)d_in[10];
    const float* imp_w2  = (const float*)d_in[11]; const float* imp_b2  = (const float*)d_in[12];
    const float* disc_w1 = (const float*)d_in[13]; const float* disc_b1 = (const float*)d_in[14];
    const float* disc_w2 = (const float*)d_in[15]; const float* disc_b2 = (const float*)d_in[16];
    const float* disc_w3 = (const float*)d_in[17]; const float* disc_b3 = (const float*)d_in[18];
    const float* cons_w1 = (const float*)d_in[19]; const float* cons_b1 = (const float*)d_in[20];
    const float* cons_w2 = (const float*)d_in[21]; const float* cons_b2 = (const float*)d_in[22];
    const float* cons_w3 = (const float*)d_in[23]; const float* cons_b3 = (const float*)d_in[24];
    const float* diff_w1 = (const float*)d_in[25]; const float* diff_b1 = (const float*)d_in[26];
    const float* diff_w2 = (const float*)d_in[27]; const float* diff_b2 = (const float*)d_in[28];
    const float* diff_w3 = (const float*)d_in[29]; const float* diff_b3 = (const float*)d_in[30];

    char* wsp = (char*)d_ws;
    size_t off = 0;
    auto alloc = [&](size_t bytes) -> void* {
        void* p = wsp + off;
        off += (bytes + 255) & ~(size_t)255;
        return p;
    };
    // bf16 transposed weights [N][K]; disc2 padded to 128 N-rows
    bfu* info1t = (bfu*)alloc((size_t)256 * 768 * 2);
    bfu* info2t = (bfu*)alloc((size_t)64 * 256 * 2);
    bfu* imp1t  = (bfu*)alloc((size_t)384 * 768 * 2);
    bfu* disc1t = (bfu*)alloc((size_t)256 * 768 * 2);
    bfu* disc2p = (bfu*)alloc((size_t)128 * 256 * 2);   // rows 64-127 zeroed
    bfu* cons1t = (bfu*)alloc((size_t)768 * 1536 * 2);
    bfu* cons2t = (bfu*)alloc((size_t)384 * 768 * 2);
    bfu* diff1t = (bfu*)alloc((size_t)768 * 1536 * 2);
    bfu* diff2t = (bfu*)alloc((size_t)384 * 768 * 2);
    float* w3pad = (float*)alloc(128 * 4);
    float* b2pad = (float*)alloc(128 * 4);
    float* part = (float*)alloc((size_t)B2 * 4);
    // zeroed accumulators: imp1 2B | imp2 2B | co B | ce B | df B | d1 2B | d2 2B
    float* accz = (float*)alloc((size_t)11 * B * 4);
    float* a_imp1 = accz;
    float* a_imp2 = accz + B2;
    float* a_co = accz + 2 * B2;
    float* a_ce = a_co + B;
    float* a_df = a_ce + B;
    float* a_d1 = a_df + B;
    float* a_d2 = a_d1 + B2;
    bfu* fA01 = (bfu*)alloc((size_t)B2 * 768 * 2);      // 50.3 MB features
    bfu* X    = (bfu*)alloc((size_t)B * 2048 * 2);      // 67.1 MB hidden
    bfu* Hd   = X;                                      // [2B x 256]
    bfu* Hi   = X + (size_t)B * 512;                    // [2B x 256] (ph1 only)
    bfu* Hc_c = X + (size_t)B * 512;                    // [B x 768] after ent
    bfu* Hc_d = X + (size_t)B * 1280;                   // [B x 768]
    (void)ws_size; (void)n_in; (void)out_size;          // ~126 MB total

    prep_k<<<dim3((11 * B + 255) / 256), 256, 0, stream>>>(accz, 11 * B, disc2p,
                                                           disc_w3, disc_b2, w3pad, b2pad);
    TPack tp;
    int blk = 0, ti = 0;
    auto setd = [&](const float* s, bfu* d, int K, int N) {
        tp.d[ti++] = {s, d, K, N, blk};
        blk += (K / 64) * (N / 64);
    };
    setd(info_w1, info1t, 768, 256);
    setd(info_w2, info2t, 256, 64);
    setd(imp_w1, imp1t, 768, 384);
    setd(disc_w1, disc1t, 768, 256);
    setd(disc_w2, disc2p, 256, 64);                     // rows 0-63 of padded
    setd(cons_w1, cons1t, 1536, 768);
    setd(cons_w2, cons2t, 768, 384);
    setd(diff_w1, diff1t, 1536, 768);
    setd(diff_w2, diff2t, 768, 384);
    transpose_k<<<dim3(blk), 256, 0, stream>>>(tp);

    // half builders
    auto h_st = [&](const bfu* W, const float* b, bfu* C, int ldc, int mode) -> Half {
        return Half{W, b, nullptr, C, nullptr, ldc, mode};
    };
    auto h_dt = [&](const bfu* W, const float* b, const float* dw, float* acc) -> Half {
        return Half{W, b, dw, nullptr, acc, 0, 1};
    };
    auto h_skip = [&](const bfu* W) -> Half {            // garbage half
        return Half{W, nullptr, nullptr, nullptr, nullptr, 0, 3};
    };
    auto seg = [&](const bfu* A, const bfu* A2, Half h0, Half h1,
                   int K, int Ksplit, int lda, int Mt) -> Seg {
        return Seg{A, A2, {h0, h1}, K, Ksplit, lda, Mt};
    };
    const bfu* fB = fA01 + (size_t)B * 768;
    const int MT2 = B2 / 256, MT1 = B / 256;   // 128 / 64 m-tiles (256-row)

    // ================= phase 1: image / text =================
    geomcast_k<<<dim3(B / 4, 2), 256, 0, stream>>>(img, txt, fA01, (bfu*)fB,
                                                   out + 0 * B, out + 1 * B, part, part + B);
    {   // BIG1: info1(erf) pair | disc1 pair | imp1-dot pair | imp1_2+skip
        SegPack p;
        p.s[0] = seg(fA01, nullptr,
                     h_st(info1t, info_b1, Hi, 256, 2),
                     h_st(info1t + (size_t)128 * 768, info_b1 + 128, Hi + 128, 256, 2),
                     768, 768, 768, MT2);
        p.s[1] = seg(fA01, nullptr,
                     h_st(disc1t, disc_b1, Hd, 256, 0),
                     h_st(disc1t + (size_t)128 * 768, disc_b1 + 128, Hd + 128, 256, 0),
                     768, 768, 768, MT2);
        p.s[2] = seg(fA01, nullptr,
                     h_dt(imp1t, imp_b1, imp_w2, a_imp1),
                     h_dt(imp1t + (size_t)128 * 768, imp_b1 + 128, imp_w2 + 128, a_imp1),
                     768, 768, 768, MT2);
        p.s[3] = seg(fA01, nullptr,
                     h_dt(imp1t + (size_t)256 * 768, imp_b1 + 256, imp_w2 + 256, a_imp1),
                     h_skip(imp1t),
                     768, 768, 768, MT2);
        gemm_k<<<dim3(4, MT2), 512, 0, stream>>>(p);
    }
    gemm64ent_k<<<dim3(B2 / 128), 256, 0, stream>>>(Hi, info2t, info_b2, part, out, B, 256, 256);
    {   // BIG2: cons1 pairs x3 (K=1536 concat) | disc2-dot + skip (K=256)
        SegPack p;
        for (int i = 0; i < 3; ++i)
            p.s[i] = seg(fA01, fB,
                         h_st(cons1t + (size_t)256 * i * 1536, cons_b1 + 256 * i,
                              Hc_c + 256 * i, 768, 0),
                         h_st(cons1t + (size_t)(256 * i + 128) * 1536, cons_b1 + 256 * i + 128,
                              Hc_c + 256 * i + 128, 768, 0),
                         1536, 768, 768, MT1);
        p.s[3] = seg(Hd, nullptr,
                     h_dt(disc2p, b2pad, w3pad, a_d1),
                     h_skip(disc2p),
                     256, 256, 256, MT2);
        gemm_k<<<dim3(4, MT2), 512, 0, stream>>>(p);
    }

    // ================= phase 2: enhanced image / text =================
    geomcast_k<<<dim3(B / 4, 2), 256, 0, stream>>>(eimg, etxt, fA01, (bfu*)fB,
                                                   out + 2 * B, out + 3 * B, nullptr, nullptr);
    {   // BIG3: imp pair | disc1 pair | imp1_2+skip (ph2 A) | cons2-dot pair + single (ph1 Hc_c)
        SegPack p;
        p.s[0] = seg(fA01, nullptr,
                     h_dt(imp1t, imp_b1, imp_w2, a_imp2),
                     h_dt(imp1t + (size_t)128 * 768, imp_b1 + 128, imp_w2 + 128, a_imp2),
                     768, 768, 768, MT2);
        p.s[1] = seg(fA01, nullptr,
                     h_st(disc1t, disc_b1, Hd, 256, 0),
                     h_st(disc1t + (size_t)128 * 768, disc_b1 + 128, Hd + 128, 256, 0),
                     768, 768, 768, MT2);
        p.s[2] = seg(fA01, nullptr,
                     h_dt(imp1t + (size_t)256 * 768, imp_b1 + 256, imp_w2 + 256, a_imp2),
                     h_skip(imp1t),
                     768, 768, 768, MT2);
        p.s[3] = seg(Hc_c, nullptr,
                     h_dt(cons2t, cons_b2, cons_w3, a_co),
                     h_dt(cons2t + (size_t)128 * 768, cons_b2 + 128, cons_w3 + 128, a_co),
                     768, 768, 768, MT1);
        p.s[4] = seg(Hc_c, nullptr,
                     h_dt(cons2t + (size_t)256 * 768, cons_b2 + 256, cons_w3 + 256, a_co),
                     h_skip(cons2t),
                     768, 768, 768, MT1);
        gemm_k<<<dim3(5, MT2), 512, 0, stream>>>(p);
    }
    {   // BIG4: (cons1_i, diff1_i) pairs x6 (shared concat A) | disc2-dot + skip
        SegPack p;
        for (int i = 0; i < 6; ++i)
            p.s[i] = seg(fA01, fB,
                         h_st(cons1t + (size_t)128 * i * 1536, cons_b1 + 128 * i,
                              Hc_c + 128 * i, 768, 0),
                         h_st(diff1t + (size_t)128 * i * 1536, diff_b1 + 128 * i,
                              Hc_d + 128 * i, 768, 0),
                         1536, 768, 768, MT1);
        p.s[6] = seg(Hd, nullptr,
                     h_dt(disc2p, b2pad, w3pad, a_d2),
                     h_skip(disc2p),
                     256, 256, 256, MT2);
        gemm_k<<<dim3(7, MT2), 512, 0, stream>>>(p);
    }
    {   // BIG5: cons2-dot pair + single (a_ce) | diff2-dot pair + single (a_df)
        SegPack p;
        p.s[0] = seg(Hc_c, nullptr,
                     h_dt(cons2t, cons_b2, cons_w3, a_ce),
                     h_dt(cons2t + (size_t)128 * 768, cons_b2 + 128, cons_w3 + 128, a_ce),
                     768, 768, 768, MT1);
        p.s[1] = seg(Hc_c, nullptr,
                     h_dt(cons2t + (size_t)256 * 768, cons_b2 + 256, cons_w3 + 256, a_ce),
                     h_skip(cons2t),
                     768, 768, 768, MT1);
        p.s[2] = seg(Hc_d, nullptr,
                     h_dt(diff2t, diff_b2, diff_w3, a_df),
                     h_dt(diff2t + (size_t)128 * 768, diff_b2 + 128, diff_w3 + 128, a_df),
                     768, 768, 768, MT1);
        p.s[3] = seg(Hc_d, nullptr,
                     h_dt(diff2t + (size_t)256 * 768, diff_b2 + 256, diff_w3 + 256, a_df),
                     h_skip(diff2t),
                     768, 768, 768, MT1);
        gemm_k<<<dim3(4, MT1), 512, 0, stream>>>(p);
    }

    finalize_k<<<dim3((B + 255) / 256), 256, 0, stream>>>(out, a_imp1, a_imp2, a_co, a_ce,
                                                          a_df, a_d1, a_d2,
                                                          imp_b2, disc_b3, cons_b3, diff_b3, B);
}

// Round 4
// 768.672 us; speedup vs baseline: 1.0263x; 1.0263x over previous
//
#include <hip/hip_runtime.h>

typedef unsigned short bfu;                                     // bf16 storage
typedef __attribute__((ext_vector_type(8))) __bf16 bf16x8;      // MFMA A/B frag
typedef __attribute__((ext_vector_type(4))) float f32x4;        // MFMA C/D frag

__device__ __forceinline__ float bf2f(bfu u) {
    unsigned int x = ((unsigned int)u) << 16;
    return __builtin_bit_cast(float, x);
}
__device__ __forceinline__ bfu f2bf(float f) {  // round-nearest-even
    unsigned int u = __builtin_bit_cast(unsigned int, f);
    unsigned int r = (u + 0x7fffu + ((u >> 16) & 1u)) >> 16;
    return (bfu)r;
}
__device__ __forceinline__ float sigm(float x) { return 1.0f / (1.0f + __expf(-x)); }
// fast tanh-GELU (~1e-3 abs err) for sigmoid-smooth heads
__device__ __forceinline__ float gelu_f(float x) {
    const float y = 0.7978845608f * (x + 0.044715f * x * x * x);
    const float t = 1.f - 2.f / (__expf(2.f * y) + 1.f);
    return 0.5f * x * (1.f + t);
}
// exact erf GELU: info head only (round(sig*10) histogram is discontinuous)
__device__ __forceinline__ float gelu_x(float x) {
    return 0.5f * x * (1.0f + erff(x * 0.70710678118654752f));
}

// async global->LDS, 16B/lane; LDS dest = wave-uniform base + lane*16.
__device__ __forceinline__ void async16(const void* g, void* l) {
    __builtin_amdgcn_global_load_lds((const __attribute__((address_space(1))) void*)g,
                                     (__attribute__((address_space(3))) void*)l, 16, 0, 0);
}

// ---------------------------------------------------------------- transpose
struct TDesc { const float* src; bfu* dst; int K, N, blk0; };
struct TPack { TDesc d[9]; };

__global__ __launch_bounds__(256) void transpose_k(TPack p) {
    const int bid = blockIdx.x;
    int j = 0;
#pragma unroll
    for (int i = 1; i < 9; ++i)
        if (bid >= p.d[i].blk0) j = i;
    const TDesc d = p.d[j];
    const int local = bid - d.blk0;
    const int tkn = d.K >> 6;
    const int tk = local % tkn, tn = local / tkn;
    const int k0 = tk * 64, n0 = tn * 64;
    __shared__ float tile[64][65];
    const int tx = threadIdx.x & 63, ty = threadIdx.x >> 6;
#pragma unroll
    for (int i = 0; i < 16; ++i) {
        const int r = ty * 16 + i;
        tile[r][tx] = d.src[(size_t)(k0 + r) * d.N + n0 + tx];
    }
    __syncthreads();
#pragma unroll
    for (int i = 0; i < 16; ++i) {
        const int n = ty * 16 + i;
        d.dst[(size_t)(n0 + n) * d.K + k0 + tx] = f2bf(tile[tx][n]);
    }
}

// --------------------------- prep: zero accumulators + build padded disc-l2
__global__ __launch_bounds__(256)
void prep_k(float* accz, int nacc, bfu* disc2pad, const float* w3,
            const float* b2, float* w3pad, float* b2pad) {
    const int i = blockIdx.x * 256 + threadIdx.x;
    if (i < nacc) accz[i] = 0.f;
    if (i < 64 * 256) disc2pad[64 * 256 + i] = 0;     // zero pad rows 64..127
    if (i < 128) {
        w3pad[i] = (i < 64) ? w3[i] : 0.f;            // pad dot weights with 0
        b2pad[i] = (i < 64) ? b2[i] : 0.f;            // pad bias with 0
    }
}

// ------------------------------------------------------- geometric + cast
__global__ __launch_bounds__(256)
void geomcast_k(const float* F0, const float* F1, bfu* D0, bfu* D1,
                float* g0, float* g1, float* p0, float* p1) {
    const int z = blockIdx.y;
    const float* F = z ? F1 : F0;
    bfu* D = z ? D1 : D0;
    float* gout = z ? g1 : g0;
    float* part = z ? p1 : p0;
    const int wave = threadIdx.x >> 6, lane = threadIdx.x & 63;
    const int row = blockIdx.x * 4 + wave;
    const float* fr = F + (size_t)row * 768;
    bfu* dr = D + (size_t)row * 768;
    float sum = 0.f, ss = 0.f, cnt = 0.f;
#pragma unroll
    for (int i = 0; i < 3; ++i) {
        const float4 v = *(const float4*)(fr + i * 256 + lane * 4);
        sum += v.x + v.y + v.z + v.w;
        ss += v.x * v.x + v.y * v.y + v.z * v.z + v.w * v.w;
        cnt += ((fabsf(v.x) > 0.01f) ? 1.f : 0.f) + ((fabsf(v.y) > 0.01f) ? 1.f : 0.f) +
               ((fabsf(v.z) > 0.01f) ? 1.f : 0.f) + ((fabsf(v.w) > 0.01f) ? 1.f : 0.f);
        ushort4 b;
        b.x = f2bf(v.x); b.y = f2bf(v.y); b.z = f2bf(v.z); b.w = f2bf(v.w);
        *(ushort4*)(dr + i * 256 + lane * 4) = b;
    }
#pragma unroll
    for (int off = 32; off; off >>= 1) {
        sum += __shfl_xor(sum, off);
        ss  += __shfl_xor(ss, off);
        cnt += __shfl_xor(cnt, off);
    }
    if (lane == 0) {
        const float n = sqrtf(ss);
        const float nq = sigm((n - 1.f) * 2.f);
        const float sp = cnt * (1.f / 768.f);
        float var = (ss - sum * sum * (1.f / 768.f)) * (1.f / 767.f);
        var = fmaxf(var, 0.f);
        const float sq = sigm(sqrtf(var) * 10.f - 1.f);
        gout[row] = (nq + sp + sq) * (1.f / 3.f);
        if (part) {
            const float cq = (n > 0.01f) ? (1.f / 768.f) : 0.f;
            const float nc = fmaxf(n, 1e-12f);
            const float dq = sigm(ss / (nc * nc) - 0.5f);
            part[row] = (cq + dq) * (1.f / 3.f);
        }
    }
}

// ------------------------------------------------------------------- GEMM
// R8: 256x256 tile + SIMPLE 2-phase stage-ahead dbuf (m230-V0 config).
// R3's 4-phase port serialized LDS-read and MFMA intervals across 8
// lockstep barriers/K-tile (MfmaUtil stuck at 24%, plus a straggler-tail
// pathology). Here: per K-tile = {stage next tile (8 async16) -> compute
// (24 ds_read_b128 + 64 MFMA, compiler-interleaved via fine lgkmcnt) ->
// __syncthreads}. The fixed stage+drain+barrier cost is amortized over 2x
// the MFMA of the 128² version (m230: 682 vs 622 TF). 128 KiB LDS -> 1
// block/CU, 8 waves. No setprio/sched_barrier (measured null on 2-phase).
// N per block = 256 -> segments fused in PAIRS of 128-col halves sharing A;
// odd counts use a skip-half (mode 3).
struct Half {
    const bfu* W;                    // this half's W rows [128][K]
    const float* bias;               // per-col bias (half-local, 128)
    const float* dotw;               // mode1: dot weights (half-local, 128)
    bfu* C;                          // mode0/2: store base (half-local cols)
    float* acc;                      // mode1: per-row fp32 accumulator
    int ldc, mode;                   // mode 3 = skip (garbage half)
};
struct Seg {
    const bfu* A; const bfu* A2;     // A2 supplies cols >= Ksplit (concat)
    Half h[2];
    int K, Ksplit, lda, Mtiles;      // Mtiles in 256-row units
};
struct SegPack { Seg s[7]; };

__global__ __launch_bounds__(512, 2)
void gemm_k(SegPack p) {
    constexpr int BK = 64;
    __shared__ bfu LDS[65536];                    // 128 KiB
    bfu* As0 = LDS;                               // 256x64 = 32 KB each
    bfu* As1 = LDS + 16384;
    bfu* Ws0 = LDS + 32768;                       // rows 0-127 = h0, 128-255 = h1
    bfu* Ws1 = LDS + 49152;

    const int NTt = gridDim.x;
    const int g = blockIdx.y * NTt + blockIdx.x;
    const int G8 = NTt * 8;                       // gridDim.y % 8 == 0 always
    const int m = (g / G8) * 8 + (g & 7);
    const int n = (g % G8) >> 3;
    const Seg sg = p.s[n];
    if (m >= sg.Mtiles) return;                   // uniform early-exit
    const int t = threadIdx.x;
    const int wave = t >> 6, lane = t & 63;
    const int row_l = lane & 15, kq = lane >> 4;
    const int m0 = m * 256;
    const int wm = wave >> 2;                     // 0..1 -> rows wm*128
    const int wn = wave & 3;                      // 0..3 -> cols wn*64
    const int half = wn >> 1;                     // which 128-col half

    // staging: thread t stages 16B chunk (t&7) of rows r0+64i (XOR-swizzled
    // source chunk; r&7 invariant since rows step by 64)
    const int r0 = t >> 3;
    const int cc = ((t & 7) ^ (r0 & 7)) << 3;
    const bfu* pA[4];
    const bfu* pW[4];
#pragma unroll
    for (int i = 0; i < 4; ++i)
        pA[i] = sg.A + (size_t)(m0 + r0 + 64 * i) * sg.lda + cc;
#pragma unroll
    for (int i = 0; i < 2; ++i) {
        pW[i]     = sg.h[0].W + (size_t)(r0 + 64 * i) * sg.K + cc;
        pW[2 + i] = sg.h[1].W + (size_t)(r0 + 64 * i) * sg.K + cc;
    }
    const int nkt = sg.K >> 6;                    // even: 4 / 12 / 24
    const int ktsw = (sg.Ksplit < sg.K) ? (sg.Ksplit >> 6) : 0x7fffffff;

    f32x4 acc[8][4] = {};

    auto stageA = [&](int sn, bfu* Ad) {
        if (sn == ktsw) {                         // concat boundary: switch A
#pragma unroll
            for (int i = 0; i < 4; ++i)
                pA[i] = sg.A2 + (size_t)(m0 + r0 + 64 * i) * sg.lda + cc;
        }
#pragma unroll
        for (int i = 0; i < 4; ++i)
            async16(pA[i], Ad + ((i * 512 + wave * 64) << 3));
#pragma unroll
        for (int i = 0; i < 4; ++i) pA[i] += BK;
    };
    auto stageW = [&](bfu* Wd) {
#pragma unroll
        for (int i = 0; i < 4; ++i)
            async16(pW[i], Wd + ((i * 512 + wave * 64) << 3));
#pragma unroll
        for (int i = 0; i < 4; ++i) pW[i] += BK;
    };
    auto ldF = [&](const bfu* base, int row, int ks) -> bf16x8 {
        return *(const bf16x8*)(base + row * BK + (((ks * 4 + kq) ^ (row & 7)) << 3));
    };
    // 24 ds_read_b128 + 64 MFMA; compiler interleaves via fine lgkmcnt
    auto compute = [&](const bfu* Ab, const bfu* Wb) {
        bf16x8 b0[4], b1[4];
#pragma unroll
        for (int ni = 0; ni < 4; ++ni) {
            const int rB = wn * 64 + ni * 16 + row_l;
            b0[ni] = ldF(Wb, rB, 0);
            b1[ni] = ldF(Wb, rB, 1);
        }
#pragma unroll
        for (int mi = 0; mi < 8; ++mi) {
            const int rA = wm * 128 + mi * 16 + row_l;
            const bf16x8 a0 = ldF(Ab, rA, 0);
            const bf16x8 a1 = ldF(Ab, rA, 1);
#pragma unroll
            for (int ni = 0; ni < 4; ++ni)
                acc[mi][ni] = __builtin_amdgcn_mfma_f32_16x16x32_bf16(a0, b0[ni], acc[mi][ni], 0, 0, 0);
#pragma unroll
            for (int ni = 0; ni < 4; ++ni)
                acc[mi][ni] = __builtin_amdgcn_mfma_f32_16x16x32_bf16(a1, b1[ni], acc[mi][ni], 0, 0, 0);
        }
    };

    // prologue: tile 0 -> buf0 (only full-latency stall per block)
    stageA(0, As0);
    stageW(Ws0);
    __syncthreads();
    for (int kt = 0; kt < nkt; kt += 2) {
        stageA(kt + 1, As1); stageW(Ws1);         // prefetch odd tile
        compute(As0, Ws0);
        __syncthreads();                          // drains prefetch (overlapped)
        if (kt + 2 < nkt) { stageA(kt + 2, As0); stageW(Ws0); }
        compute(As1, Ws1);
        __syncthreads();
    }

    // ---- epilogue; C/D layout: col=lane&15, row=quad*4+reg (m89/m91) ----
    const Half hh = sg.h[half];
    if (hh.mode == 0) {
#pragma unroll
        for (int ni = 0; ni < 4; ++ni) {
            const int lcol = (wn & 1) * 64 + ni * 16 + row_l;
            const float bv = hh.bias[lcol];
#pragma unroll
            for (int mi = 0; mi < 8; ++mi)
#pragma unroll
                for (int r = 0; r < 4; ++r) {
                    const int row = m0 + wm * 128 + mi * 16 + kq * 4 + r;
                    hh.C[(size_t)row * hh.ldc + lcol] = f2bf(gelu_f(acc[mi][ni][r] + bv));
                }
        }
    } else if (hh.mode == 2) {
#pragma unroll
        for (int ni = 0; ni < 4; ++ni) {
            const int lcol = (wn & 1) * 64 + ni * 16 + row_l;
            const float bv = hh.bias[lcol];
#pragma unroll
            for (int mi = 0; mi < 8; ++mi)
#pragma unroll
                for (int r = 0; r < 4; ++r) {
                    const int row = m0 + wm * 128 + mi * 16 + kq * 4 + r;
                    hh.C[(size_t)row * hh.ldc + lcol] = f2bf(gelu_x(acc[mi][ni][r] + bv));
                }
        }
    } else if (hh.mode == 1) {
#pragma unroll
        for (int mi = 0; mi < 8; ++mi)
#pragma unroll
            for (int r = 0; r < 4; ++r) {
                float s = 0.f;
#pragma unroll
                for (int ni = 0; ni < 4; ++ni) {
                    const int lcol = (wn & 1) * 64 + ni * 16 + row_l;
                    s += hh.dotw[lcol] * gelu_f(acc[mi][ni][r] + hh.bias[lcol]);
                }
                s += __shfl_xor(s, 1); s += __shfl_xor(s, 2);
                s += __shfl_xor(s, 4); s += __shfl_xor(s, 8);
                if (row_l == 0)
                    atomicAdd(hh.acc + m0 + wm * 128 + mi * 16 + kq * 4 + r, s);
            }
    }
    // mode 3: skip half
}

// -------------------------------- BN=64 GEMM + fused entropy (info l2)
__global__ __launch_bounds__(256)
void gemm64ent_k(const bfu* __restrict__ A, const bfu* __restrict__ W,
                 const float* __restrict__ bias, const float* __restrict__ part,
                 float* out, int B, int K, int lda) {
    constexpr int BK = 64, MT = 2, NT = 4;
    __shared__ __align__(16) float smemf[12288];  // 48KB: dbuf staging | ET union
    bfu* As0 = (bfu*)smemf;                       // 128x64 bf16 = 16 KB
    bfu* Ws0 = (bfu*)smemf + 128 * BK;            // 64x64 bf16 = 8 KB
    bfu* As1 = (bfu*)smemf + 192 * BK;
    bfu* Ws1 = (bfu*)smemf + 320 * BK;
    float* ET = smemf;                            // 128 x 65 fp32 after K-loop
    const int t = threadIdx.x;
    const int wave = t >> 6, lane = t & 63;
    const int row_l = lane & 15, kq = lane >> 4;
    const int m0 = blockIdx.x * 128;
    const int wrow0 = wave * 32;
    f32x4 acc[MT][NT] = {};
    const int nkt = K / BK;

    const int r0 = t >> 3;
    const int cc = ((t & 7) ^ (r0 & 7)) << 3;
    const size_t strA = (size_t)32 * lda;
    const size_t strW = (size_t)32 * K;
    const bfu* pA[4];
    const bfu* pW[2];
#pragma unroll
    for (int i = 0; i < 4; ++i)
        pA[i] = A + (size_t)(m0 + r0) * lda + cc + i * strA;
#pragma unroll
    for (int i = 0; i < 2; ++i)
        pW[i] = W + (size_t)r0 * K + cc + i * strW;

    auto stage = [&](bfu* Ad, bfu* Wd) {
#pragma unroll
        for (int i = 0; i < 4; ++i)
            async16(pA[i], Ad + ((i * 256 + wave * 64) << 3));
#pragma unroll
        for (int i = 0; i < 2; ++i)
            async16(pW[i], Wd + ((i * 256 + wave * 64) << 3));
#pragma unroll
        for (int i = 0; i < 4; ++i) pA[i] += BK;
#pragma unroll
        for (int i = 0; i < 2; ++i) pW[i] += BK;
    };
    auto compute = [&](const bfu* Ab, const bfu* Wb) {
#pragma unroll
        for (int ks = 0; ks < 2; ++ks) {
            bf16x8 af[MT], bfr[NT];
#pragma unroll
            for (int mi = 0; mi < MT; ++mi) {
                const int rA = wrow0 + mi * 16 + row_l;
                af[mi] = *(const bf16x8*)(Ab + rA * BK + (((ks * 4 + kq) ^ (rA & 7)) << 3));
            }
#pragma unroll
            for (int ni = 0; ni < NT; ++ni) {
                const int rB = ni * 16 + row_l;
                bfr[ni] = *(const bf16x8*)(Wb + rB * BK + (((ks * 4 + kq) ^ (rB & 7)) << 3));
            }
#pragma unroll
            for (int mi = 0; mi < MT; ++mi)
#pragma unroll
                for (int ni = 0; ni < NT; ++ni)
                    acc[mi][ni] = __builtin_amdgcn_mfma_f32_16x16x32_bf16(af[mi], bfr[ni], acc[mi][ni], 0, 0, 0);
        }
    };

    stage(As0, Ws0);
    __syncthreads();
    for (int kt = 0; kt < nkt; kt += 2) {
        stage(As1, Ws1);
        compute(As0, Ws0);
        __syncthreads();
        if (kt + 2 < nkt) stage(As0, Ws0);
        compute(As1, Ws1);
        __syncthreads();
    }

    // dump 128x64 fp32 logits (no activation) to LDS
#pragma unroll
    for (int mi = 0; mi < MT; ++mi)
#pragma unroll
        for (int ni = 0; ni < NT; ++ni) {
            const int col = ni * 16 + row_l;
            const float bv = bias[col];
#pragma unroll
            for (int r = 0; r < 4; ++r)
                ET[(wrow0 + mi * 16 + kq * 4 + r) * 65 + col] = acc[mi][ni][r] + bv;
        }
    __syncthreads();
    if (t < 128) {   // one thread per row: histogram entropy over 64 logits
        int cnt[11];
#pragma unroll
        for (int b = 0; b < 11; ++b) cnt[b] = 0;
        for (int j = 0; j < 64; ++j) {
            const int d = (int)rintf(sigm(ET[t * 65 + j]) * 10.f);
#pragma unroll
            for (int b = 0; b < 11; ++b) cnt[b] += (d == b);
        }
        float ent = 0.f;
#pragma unroll
        for (int b = 0; b < 11; ++b) {
            if (cnt[b] > 0) {
                const float pp = (float)cnt[b] * (1.f / 64.f);
                ent -= pp * __logf(pp + 1e-8f);
            }
        }
        const int row = m0 + t;
        const int orow = (row < B) ? 4 : 5;
        const int rl = (row < B) ? row : row - B;
        out[(size_t)orow * B + rl] = part[row] + sigm(ent - 2.f) * (1.f / 3.f);
    }
}

// --------------- finalize: sigmoids over fused-dot accumulators + overall
__global__ __launch_bounds__(256)
void finalize_k(float* out, const float* a_imp1, const float* a_imp2,
                const float* a_co, const float* a_ce, const float* a_df,
                const float* a_d1, const float* a_d2,
                const float* imp_b2, const float* disc_b3,
                const float* cons_b3, const float* diff_b3, int B) {
    const int i = blockIdx.x * 256 + threadIdx.x;
    if (i >= B) return;
    const float ib = imp_b2[0], db = disc_b3[0], cb = cons_b3[0], fb = diff_b3[0];
    const float o6 = sigm(a_co[i] + cb);
    const float o7 = sigm(a_ce[i] + cb);
    const float o8 = sigm(a_imp1[i] + ib);
    const float o9 = sigm(a_imp1[B + i] + ib);
    out[6 * B + i] = o6;
    out[7 * B + i] = o7;
    out[8 * B + i] = o8;
    out[9 * B + i] = o9;
    out[10 * B + i] = sigm(a_imp2[i] + ib);
    out[11 * B + i] = sigm(a_imp2[B + i] + ib);
    out[12 * B + i] = sigm(a_d1[i] + db);
    out[14 * B + i] = sigm(a_d1[B + i] + db);
    out[13 * B + i] = sigm(a_d2[i] + db);
    out[15 * B + i] = sigm(a_d2[B + i] + db);
    out[16 * B + i] = sigm(a_df[i] + fb);
    const float v = out[0 * B + i] + out[1 * B + i] + out[4 * B + i] + out[5 * B + i] +
                    o7 + 0.5f * (o8 + o9);
    out[17 * B + i] = v * (1.f / 6.f);
}

extern "C" void kernel_launch(void* const* d_in, const int* in_sizes, int n_in,
                              void* d_out, int out_size, void* d_ws, size_t ws_size,
                              hipStream_t stream) {
    const int B = in_sizes[4];  // 16384
    const int B2 = 2 * B;
    float* out = (float*)d_out;
    const float* img  = (const float*)d_in[0];
    const float* txt  = (const float*)d_in[1];
    const float* eimg = (const float*)d_in[2];
    const float* etxt = (const float*)d_in[3];
    const float* info_w1 = (const float*)d_in[5];  const float* info_b1 = (const float*)d_in[6];
    const float* info_w2 = (const float*)d_in[7];  const float* info_b2 = (const float*)d_in[8];
    const float* imp_w1  = (const float*)d_in[9];  const float* imp_b1  = (const float*)d_in[10];
    const float* imp_w2  = (const float*)d_in[11]; const float* imp_b2  = (const float*)d_in[12];
    const float* disc_w1 = (const float*)d_in[13]; const float* disc_b1 = (const float*)d_in[14];
    const float* disc_w2 = (const float*)d_in[15]; const float* disc_b2 = (const float*)d_in[16];
    const float* disc_w3 = (const float*)d_in[17]; const float* disc_b3 = (const float*)d_in[18];
    const float* cons_w1 = (const float*)d_in[19]; const float* cons_b1 = (const float*)d_in[20];
    const float* cons_w2 = (const float*)d_in[21]; const float* cons_b2 = (const float*)d_in[22];
    const float* cons_w3 = (const float*)d_in[23]; const float* cons_b3 = (const float*)d_in[24];
    const float* diff_w1 = (const float*)d_in[25]; const float* diff_b1 = (const float*)d_in[26];
    const float* diff_w2 = (const float*)d_in[27]; const float* diff_b2 = (const float*)d_in[28];
    const float* diff_w3 = (const float*)d_in[29]; const float* diff_b3 = (const float*)d_in[30];

    char* wsp = (char*)d_ws;
    size_t off = 0;
    auto alloc = [&](size_t bytes) -> void* {
        void* p = wsp + off;
        off += (bytes + 255) & ~(size_t)255;
        return p;
    };
    // bf16 transposed weights [N][K]; disc2 padded to 128 N-rows
    bfu* info1t = (bfu*)alloc((size_t)256 * 768 * 2);
    bfu* info2t = (bfu*)alloc((size_t)64 * 256 * 2);
    bfu* imp1t  = (bfu*)alloc((size_t)384 * 768 * 2);
    bfu* disc1t = (bfu*)alloc((size_t)256 * 768 * 2);
    bfu* disc2p = (bfu*)alloc((size_t)128 * 256 * 2);   // rows 64-127 zeroed
    bfu* cons1t = (bfu*)alloc((size_t)768 * 1536 * 2);
    bfu* cons2t = (bfu*)alloc((size_t)384 * 768 * 2);
    bfu* diff1t = (bfu*)alloc((size_t)768 * 1536 * 2);
    bfu* diff2t = (bfu*)alloc((size_t)384 * 768 * 2);
    float* w3pad = (float*)alloc(128 * 4);
    float* b2pad = (float*)alloc(128 * 4);
    float* part = (float*)alloc((size_t)B2 * 4);
    // zeroed accumulators: imp1 2B | imp2 2B | co B | ce B | df B | d1 2B | d2 2B
    float* accz = (float*)alloc((size_t)11 * B * 4);
    float* a_imp1 = accz;
    float* a_imp2 = accz + B2;
    float* a_co = accz + 2 * B2;
    float* a_ce = a_co + B;
    float* a_df = a_ce + B;
    float* a_d1 = a_df + B;
    float* a_d2 = a_d1 + B2;
    bfu* fA01 = (bfu*)alloc((size_t)B2 * 768 * 2);      // 50.3 MB features
    bfu* X    = (bfu*)alloc((size_t)B * 2048 * 2);      // 67.1 MB hidden
    bfu* Hd   = X;                                      // [2B x 256]
    bfu* Hi   = X + (size_t)B * 512;                    // [2B x 256] (ph1 only)
    bfu* Hc_c = X + (size_t)B * 512;                    // [B x 768] after ent
    bfu* Hc_d = X + (size_t)B * 1280;                   // [B x 768]
    (void)ws_size; (void)n_in; (void)out_size;          // ~126 MB total

    prep_k<<<dim3((11 * B + 255) / 256), 256, 0, stream>>>(accz, 11 * B, disc2p,
                                                           disc_w3, disc_b2, w3pad, b2pad);
    TPack tp;
    int blk = 0, ti = 0;
    auto setd = [&](const float* s, bfu* d, int K, int N) {
        tp.d[ti++] = {s, d, K, N, blk};
        blk += (K / 64) * (N / 64);
    };
    setd(info_w1, info1t, 768, 256);
    setd(info_w2, info2t, 256, 64);
    setd(imp_w1, imp1t, 768, 384);
    setd(disc_w1, disc1t, 768, 256);
    setd(disc_w2, disc2p, 256, 64);                     // rows 0-63 of padded
    setd(cons_w1, cons1t, 1536, 768);
    setd(cons_w2, cons2t, 768, 384);
    setd(diff_w1, diff1t, 1536, 768);
    setd(diff_w2, diff2t, 768, 384);
    transpose_k<<<dim3(blk), 256, 0, stream>>>(tp);

    // half builders
    auto h_st = [&](const bfu* W, const float* b, bfu* C, int ldc, int mode) -> Half {
        return Half{W, b, nullptr, C, nullptr, ldc, mode};
    };
    auto h_dt = [&](const bfu* W, const float* b, const float* dw, float* acc) -> Half {
        return Half{W, b, dw, nullptr, acc, 0, 1};
    };
    auto h_skip = [&](const bfu* W) -> Half {            // garbage half
        return Half{W, nullptr, nullptr, nullptr, nullptr, 0, 3};
    };
    auto seg = [&](const bfu* A, const bfu* A2, Half h0, Half h1,
                   int K, int Ksplit, int lda, int Mt) -> Seg {
        return Seg{A, A2, {h0, h1}, K, Ksplit, lda, Mt};
    };
    const bfu* fB = fA01 + (size_t)B * 768;
    const int MT2 = B2 / 256, MT1 = B / 256;   // 128 / 64 m-tiles (256-row)

    // ================= phase 1: image / text =================
    geomcast_k<<<dim3(B / 4, 2), 256, 0, stream>>>(img, txt, fA01, (bfu*)fB,
                                                   out + 0 * B, out + 1 * B, part, part + B);
    {   // BIG1: info1(erf) pair | disc1 pair | imp1-dot pair | imp1_2+skip
        SegPack p;
        p.s[0] = seg(fA01, nullptr,
                     h_st(info1t, info_b1, Hi, 256, 2),
                     h_st(info1t + (size_t)128 * 768, info_b1 + 128, Hi + 128, 256, 2),
                     768, 768, 768, MT2);
        p.s[1] = seg(fA01, nullptr,
                     h_st(disc1t, disc_b1, Hd, 256, 0),
                     h_st(disc1t + (size_t)128 * 768, disc_b1 + 128, Hd + 128, 256, 0),
                     768, 768, 768, MT2);
        p.s[2] = seg(fA01, nullptr,
                     h_dt(imp1t, imp_b1, imp_w2, a_imp1),
                     h_dt(imp1t + (size_t)128 * 768, imp_b1 + 128, imp_w2 + 128, a_imp1),
                     768, 768, 768, MT2);
        p.s[3] = seg(fA01, nullptr,
                     h_dt(imp1t + (size_t)256 * 768, imp_b1 + 256, imp_w2 + 256, a_imp1),
                     h_skip(imp1t),
                     768, 768, 768, MT2);
        gemm_k<<<dim3(4, MT2), 512, 0, stream>>>(p);
    }
    gemm64ent_k<<<dim3(B2 / 128), 256, 0, stream>>>(Hi, info2t, info_b2, part, out, B, 256, 256);
    {   // BIG2: cons1 pairs x3 (K=1536 concat) | disc2-dot + skip (K=256)
        SegPack p;
        for (int i = 0; i < 3; ++i)
            p.s[i] = seg(fA01, fB,
                         h_st(cons1t + (size_t)256 * i * 1536, cons_b1 + 256 * i,
                              Hc_c + 256 * i, 768, 0),
                         h_st(cons1t + (size_t)(256 * i + 128) * 1536, cons_b1 + 256 * i + 128,
                              Hc_c + 256 * i + 128, 768, 0),
                         1536, 768, 768, MT1);
        p.s[3] = seg(Hd, nullptr,
                     h_dt(disc2p, b2pad, w3pad, a_d1),
                     h_skip(disc2p),
                     256, 256, 256, MT2);
        gemm_k<<<dim3(4, MT2), 512, 0, stream>>>(p);
    }

    // ================= phase 2: enhanced image / text =================
    geomcast_k<<<dim3(B / 4, 2), 256, 0, stream>>>(eimg, etxt, fA01, (bfu*)fB,
                                                   out + 2 * B, out + 3 * B, nullptr, nullptr);
    {   // BIG3: imp pair | disc1 pair | imp1_2+skip (ph2 A) | cons2-dot pair + single (ph1 Hc_c)
        SegPack p;
        p.s[0] = seg(fA01, nullptr,
                     h_dt(imp1t, imp_b1, imp_w2, a_imp2),
                     h_dt(imp1t + (size_t)128 * 768, imp_b1 + 128, imp_w2 + 128, a_imp2),
                     768, 768, 768, MT2);
        p.s[1] = seg(fA01, nullptr,
                     h_st(disc1t, disc_b1, Hd, 256, 0),
                     h_st(disc1t + (size_t)128 * 768, disc_b1 + 128, Hd + 128, 256, 0),
                     768, 768, 768, MT2);
        p.s[2] = seg(fA01, nullptr,
                     h_dt(imp1t + (size_t)256 * 768, imp_b1 + 256, imp_w2 + 256, a_imp2),
                     h_skip(imp1t),
                     768, 768, 768, MT2);
        p.s[3] = seg(Hc_c, nullptr,
                     h_dt(cons2t, cons_b2, cons_w3, a_co),
                     h_dt(cons2t + (size_t)128 * 768, cons_b2 + 128, cons_w3 + 128, a_co),
                     768, 768, 768, MT1);
        p.s[4] = seg(Hc_c, nullptr,
                     h_dt(cons2t + (size_t)256 * 768, cons_b2 + 256, cons_w3 + 256, a_co),
                     h_skip(cons2t),
                     768, 768, 768, MT1);
        gemm_k<<<dim3(5, MT2), 512, 0, stream>>>(p);
    }
    {   // BIG4: (cons1_i, diff1_i) pairs x6 (shared concat A) | disc2-dot + skip
        SegPack p;
        for (int i = 0; i < 6; ++i)
            p.s[i] = seg(fA01, fB,
                         h_st(cons1t + (size_t)128 * i * 1536, cons_b1 + 128 * i,
                              Hc_c + 128 * i, 768, 0),
                         h_st(diff1t + (size_t)128 * i * 1536, diff_b1 + 128 * i,
                              Hc_d + 128 * i, 768, 0),
                         1536, 768, 768, MT1);
        p.s[6] = seg(Hd, nullptr,
                     h_dt(disc2p, b2pad, w3pad, a_d2),
                     h_skip(disc2p),
                     256, 256, 256, MT2);
        gemm_k<<<dim3(7, MT2), 512, 0, stream>>>(p);
    }
    {   // BIG5: cons2-dot pair + single (a_ce) | diff2-dot pair + single (a_df)
        SegPack p;
        p.s[0] = seg(Hc_c, nullptr,
                     h_dt(cons2t, cons_b2, cons_w3, a_ce),
                     h_dt(cons2t + (size_t)128 * 768, cons_b2 + 128, cons_w3 + 128, a_ce),
                     768, 768, 768, MT1);
        p.s[1] = seg(Hc_c, nullptr,
                     h_dt(cons2t + (size_t)256 * 768, cons_b2 + 256, cons_w3 + 256, a_ce),
                     h_skip(cons2t),
                     768, 768, 768, MT1);
        p.s[2] = seg(Hc_d, nullptr,
                     h_dt(diff2t, diff_b2, diff_w3, a_df),
                     h_dt(diff2t + (size_t)128 * 768, diff_b2 + 128, diff_w3 + 128, a_df),
                     768, 768, 768, MT1);
        p.s[3] = seg(Hc_d, nullptr,
                     h_dt(diff2t + (size_t)256 * 768, diff_b2 + 256, diff_w3 + 256, a_df),
                     h_skip(diff2t),
                     768, 768, 768, MT1);
        gemm_k<<<dim3(4, MT1), 512, 0, stream>>>(p);
    }

    finalize_k<<<dim3((B + 255) / 256), 256, 0, stream>>>(out, a_imp1, a_imp2, a_co, a_ce,
                                                          a_df, a_d1, a_d2,
                                                          imp_b2, disc_b3, cons_b3, diff_b3, B);
}

// Round 6
// 675.933 us; speedup vs baseline: 1.1672x; 1.1372x over previous
//
#include <hip/hip_runtime.h>

typedef unsigned short bfu;                                     // bf16 storage
typedef __attribute__((ext_vector_type(8))) __bf16 bf16x8;      // MFMA A/B frag
typedef __attribute__((ext_vector_type(4))) float f32x4;        // MFMA C/D frag

__device__ __forceinline__ float bf2f(bfu u) {
    unsigned int x = ((unsigned int)u) << 16;
    return __builtin_bit_cast(float, x);
}
__device__ __forceinline__ bfu f2bf(float f) {  // round-nearest-even
    unsigned int u = __builtin_bit_cast(unsigned int, f);
    unsigned int r = (u + 0x7fffu + ((u >> 16) & 1u)) >> 16;
    return (bfu)r;
}
__device__ __forceinline__ float sigm(float x) { return 1.0f / (1.0f + __expf(-x)); }
// fast tanh-GELU (~1e-3 abs err) for sigmoid-smooth heads
__device__ __forceinline__ float gelu_f(float x) {
    const float y = 0.7978845608f * (x + 0.044715f * x * x * x);
    const float t = 1.f - 2.f / (__expf(2.f * y) + 1.f);
    return 0.5f * x * (1.f + t);
}
// exact erf GELU: info head only (round(sig*10) histogram is discontinuous)
__device__ __forceinline__ float gelu_x(float x) {
    return 0.5f * x * (1.0f + erff(x * 0.70710678118654752f));
}

// async global->LDS, 16B/lane; LDS dest = wave-uniform base + lane*16.
__device__ __forceinline__ void async16(const void* g, void* l) {
    __builtin_amdgcn_global_load_lds((const __attribute__((address_space(1))) void*)g,
                                     (__attribute__((address_space(3))) void*)l, 16, 0, 0);
}

// ------------------------------------------------ setup mega-kernel
// R6 (= R5 resubmit; R5 bench was an infra failure, source audited clean):
// prep + 9 weight-transposes + geomcast (1 or 2 phases) in ONE launch —
// all mutually independent. Cuts per-launch ramp/tail/gap overhead (11->7
// launches total). Transpose branch uses the 64x65 LDS tile; others none.
struct TDesc { const float* src; bfu* dst; int K, N, blk0; };
struct TPack { TDesc d[9]; };
struct GeoArgs { const float* F; bfu* D; float* gout; float* part; };
struct SetupPack {
    TPack tp; int nT, nP, Bq;        // Bq = B/4 blocks per geom entry
    float* accz; int nacc; bfu* disc2pad;
    const float* w3f; const float* b2f; float* w3pad; float* b2pad;
    GeoArgs g[4]; int ng;
};

__global__ __launch_bounds__(256) void setup_k(SetupPack s) {
    __shared__ float tile[64][65];
    const int bid = blockIdx.x;
    if (bid < s.nT) {                 // ---------------- transpose branch
        int j = 0;
#pragma unroll
        for (int i = 1; i < 9; ++i)
            if (bid >= s.tp.d[i].blk0) j = i;
        const TDesc d = s.tp.d[j];
        const int local = bid - d.blk0;
        const int tkn = d.K >> 6;
        const int tk = local % tkn, tn = local / tkn;
        const int k0 = tk * 64, n0 = tn * 64;
        const int tx = threadIdx.x & 63, ty = threadIdx.x >> 6;
#pragma unroll
        for (int i = 0; i < 16; ++i) {
            const int r = ty * 16 + i;
            tile[r][tx] = d.src[(size_t)(k0 + r) * d.N + n0 + tx];
        }
        __syncthreads();
#pragma unroll
        for (int i = 0; i < 16; ++i) {
            const int n = ty * 16 + i;
            d.dst[(size_t)(n0 + n) * d.K + k0 + tx] = f2bf(tile[tx][n]);
        }
        return;
    }
    int b2 = bid - s.nT;
    if (b2 < s.nP) {                  // ---------------- prep branch
        const int i = b2 * 256 + threadIdx.x;
        if (i < s.nacc) s.accz[i] = 0.f;
        if (i < 64 * 256) s.disc2pad[64 * 256 + i] = 0;
        if (i < 128) {
            s.w3pad[i] = (i < 64) ? s.w3f[i] : 0.f;
            s.b2pad[i] = (i < 64) ? s.b2f[i] : 0.f;
        }
        return;
    }
    b2 -= s.nP;                       // ---------------- geomcast branch
    const int gi = b2 / s.Bq, rb = b2 % s.Bq;
    const GeoArgs ga = s.g[gi];
    const int wave = threadIdx.x >> 6, lane = threadIdx.x & 63;
    const int row = rb * 4 + wave;
    const float* fr = ga.F + (size_t)row * 768;
    bfu* dr = ga.D + (size_t)row * 768;
    float sum = 0.f, ss = 0.f, cnt = 0.f;
#pragma unroll
    for (int i = 0; i < 3; ++i) {
        const float4 v = *(const float4*)(fr + i * 256 + lane * 4);
        sum += v.x + v.y + v.z + v.w;
        ss += v.x * v.x + v.y * v.y + v.z * v.z + v.w * v.w;
        cnt += ((fabsf(v.x) > 0.01f) ? 1.f : 0.f) + ((fabsf(v.y) > 0.01f) ? 1.f : 0.f) +
               ((fabsf(v.z) > 0.01f) ? 1.f : 0.f) + ((fabsf(v.w) > 0.01f) ? 1.f : 0.f);
        ushort4 b;
        b.x = f2bf(v.x); b.y = f2bf(v.y); b.z = f2bf(v.z); b.w = f2bf(v.w);
        *(ushort4*)(dr + i * 256 + lane * 4) = b;
    }
#pragma unroll
    for (int off = 32; off; off >>= 1) {
        sum += __shfl_xor(sum, off);
        ss  += __shfl_xor(ss, off);
        cnt += __shfl_xor(cnt, off);
    }
    if (lane == 0) {
        const float n = sqrtf(ss);
        const float nq = sigm((n - 1.f) * 2.f);
        const float sp = cnt * (1.f / 768.f);
        float var = (ss - sum * sum * (1.f / 768.f)) * (1.f / 767.f);
        var = fmaxf(var, 0.f);
        const float sq = sigm(sqrtf(var) * 10.f - 1.f);
        ga.gout[row] = (nq + sp + sq) * (1.f / 3.f);
        if (ga.part) {
            const float cq = (n > 0.01f) ? (1.f / 768.f) : 0.f;
            const float nc = fmaxf(n, 1e-12f);
            const float dq = sigm(ss / (nc * nc) - 0.5f);
            ga.part[row] = (cq + dq) * (1.f / 3.f);
        }
    }
}

// standalone geomcast for the fallback (!bigws) schedule
__global__ __launch_bounds__(256)
void geomcast_k(const float* F0, const float* F1, bfu* D0, bfu* D1,
                float* g0, float* g1, float* p0, float* p1) {
    const int z = blockIdx.y;
    const float* F = z ? F1 : F0;
    bfu* D = z ? D1 : D0;
    float* gout = z ? g1 : g0;
    float* part = z ? p1 : p0;
    const int wave = threadIdx.x >> 6, lane = threadIdx.x & 63;
    const int row = blockIdx.x * 4 + wave;
    const float* fr = F + (size_t)row * 768;
    bfu* dr = D + (size_t)row * 768;
    float sum = 0.f, ss = 0.f, cnt = 0.f;
#pragma unroll
    for (int i = 0; i < 3; ++i) {
        const float4 v = *(const float4*)(fr + i * 256 + lane * 4);
        sum += v.x + v.y + v.z + v.w;
        ss += v.x * v.x + v.y * v.y + v.z * v.z + v.w * v.w;
        cnt += ((fabsf(v.x) > 0.01f) ? 1.f : 0.f) + ((fabsf(v.y) > 0.01f) ? 1.f : 0.f) +
               ((fabsf(v.z) > 0.01f) ? 1.f : 0.f) + ((fabsf(v.w) > 0.01f) ? 1.f : 0.f);
        ushort4 b;
        b.x = f2bf(v.x); b.y = f2bf(v.y); b.z = f2bf(v.z); b.w = f2bf(v.w);
        *(ushort4*)(dr + i * 256 + lane * 4) = b;
    }
#pragma unroll
    for (int off = 32; off; off >>= 1) {
        sum += __shfl_xor(sum, off);
        ss  += __shfl_xor(ss, off);
        cnt += __shfl_xor(cnt, off);
    }
    if (lane == 0) {
        const float n = sqrtf(ss);
        const float nq = sigm((n - 1.f) * 2.f);
        const float sp = cnt * (1.f / 768.f);
        float var = (ss - sum * sum * (1.f / 768.f)) * (1.f / 767.f);
        var = fmaxf(var, 0.f);
        const float sq = sigm(sqrtf(var) * 10.f - 1.f);
        gout[row] = (nq + sp + sq) * (1.f / 3.f);
        if (part) {
            const float cq = (n > 0.01f) ? (1.f / 768.f) : 0.f;
            const float nc = fmaxf(n, 1e-12f);
            const float dq = sigm(ss / (nc * nc) - 0.5f);
            part[row] = (cq + dq) * (1.f / 3.f);
        }
    }
}

// ------------------------------------------------------------------- GEMM
// Core = the R1-proven 128x128 / 4-wave / BK=64 / dbuf stage-ahead loop
// (best measured: 124 us BIG4, ~660 TF — the 2-phase structure ceiling;
// R2 counted-vmcnt and R3/R4 256² variants were all neutral-to-worse).
// Body factored into a device fn so the disc2+entropy merged kernel reuses it.
struct Seg {
    const bfu* A; const bfu* A2;    // A2 supplies cols >= Ksplit (concat)
    const bfu* W;                    // this tile's W rows [128][K]
    const float* bias;               // per-col bias (tile-local, 128)
    const float* dotw;               // mode1: dot weights (tile-local, 128)
    bfu* C;                          // mode0/2: store base (tile-local cols)
    float* acc;                      // mode1: per-row fp32 accumulator
    int ldc, mode, K, Ksplit, lda, Mtiles;
};
struct SegPack { Seg s[13]; };

__device__ __forceinline__ void gemm_body(const SegPack& p, int bx, int by, int NTt, bfu* LDSb) {
    constexpr int BK = 64, MT = 4, NT = 4;
    bfu* As0 = LDSb;                              // 4 x 16 KB
    bfu* Ws0 = LDSb + 8192;
    bfu* As1 = LDSb + 16384;
    bfu* Ws1 = LDSb + 24576;
    const int g = by * NTt + bx;
    const int G8 = NTt * 8;                       // gridDim.y % 8 == 0 always
    const int m = (g / G8) * 8 + (g & 7);         // m%8 = XCD -> A L2-resident
    const int n = (g % G8) >> 3;
    const Seg sg = p.s[n];
    if (m >= sg.Mtiles) return;                   // uniform early-exit
    const int t = threadIdx.x;
    const int wave = t >> 6, lane = t & 63;
    const int row_l = lane & 15, kq = lane >> 4;
    const int m0 = m * 128;
    const int wm = wave >> 1, wn = wave & 1;
    const int wrow0 = wm * 64, wcol0 = wn * 64;

    // rolling per-lane staging pointers (XOR-swizzled source chunk; r&7 is
    // i-independent since rows step by 32)
    const int r0 = t >> 3;
    const int cc = ((t & 7) ^ (r0 & 7)) << 3;
    const size_t strA = (size_t)32 * sg.lda;
    const size_t strW = (size_t)32 * sg.K;
    const bfu* pA[4];
    const bfu* pW[4];
#pragma unroll
    for (int i = 0; i < 4; ++i) {
        pA[i] = sg.A + (size_t)(m0 + r0) * sg.lda + cc + i * strA;
        pW[i] = sg.W + (size_t)r0 * sg.K + cc + i * strW;
    }
    const int nkt = sg.K >> 6;                    // even for all segments
    const int ktsw = (sg.Ksplit < sg.K) ? (sg.Ksplit >> 6) : 0x7fffffff;

    f32x4 acc[MT][NT] = {};

    auto stage = [&](bfu* Ad, bfu* Wd, int sn) {
        if (sn == ktsw) {                         // concat boundary: switch A
#pragma unroll
            for (int i = 0; i < 4; ++i)
                pA[i] = sg.A2 + (size_t)(m0 + r0) * sg.lda + cc + i * strA;
        }
#pragma unroll
        for (int i = 0; i < 4; ++i)
            async16(pA[i], Ad + ((i * 256 + wave * 64) << 3));
#pragma unroll
        for (int i = 0; i < 4; ++i)
            async16(pW[i], Wd + ((i * 256 + wave * 64) << 3));
#pragma unroll
        for (int i = 0; i < 4; ++i) { pA[i] += BK; pW[i] += BK; }
    };
    auto compute = [&](const bfu* Ab, const bfu* Wb) {
#pragma unroll
        for (int ks = 0; ks < 2; ++ks) {
            bf16x8 af[MT], bfr[NT];
#pragma unroll
            for (int mi = 0; mi < MT; ++mi) {
                const int rA = wrow0 + mi * 16 + row_l;
                af[mi] = *(const bf16x8*)(Ab + rA * BK + (((ks * 4 + kq) ^ (rA & 7)) << 3));
            }
#pragma unroll
            for (int ni = 0; ni < NT; ++ni) {
                const int rB = wcol0 + ni * 16 + row_l;
                bfr[ni] = *(const bf16x8*)(Wb + rB * BK + (((ks * 4 + kq) ^ (rB & 7)) << 3));
            }
#pragma unroll
            for (int mi = 0; mi < MT; ++mi)
#pragma unroll
                for (int ni = 0; ni < NT; ++ni)
                    acc[mi][ni] = __builtin_amdgcn_mfma_f32_16x16x32_bf16(af[mi], bfr[ni], acc[mi][ni], 0, 0, 0);
        }
    };

    // prologue: tile 0 -> buf0 (only full-latency stall per block)
    stage(As0, Ws0, 0);
    __syncthreads();
    for (int kt = 0; kt < nkt; kt += 2) {
        stage(As1, Ws1, kt + 1);                  // prefetch odd tile
        compute(As0, Ws0);
        __syncthreads();                          // drains prefetch (overlapped)
        if (kt + 2 < nkt) stage(As0, Ws0, kt + 2);
        compute(As1, Ws1);
        __syncthreads();
    }

    // C/D layout: col=lane&15, row=quad*4+reg (m89/m91-verified)
    if (sg.mode == 0) {
#pragma unroll
        for (int ni = 0; ni < NT; ++ni) {
            const int col = wcol0 + ni * 16 + row_l;
            const float bv = sg.bias[col];
#pragma unroll
            for (int mi = 0; mi < MT; ++mi)
#pragma unroll
                for (int r = 0; r < 4; ++r) {
                    const int row = m0 + wrow0 + mi * 16 + kq * 4 + r;
                    sg.C[(size_t)row * sg.ldc + col] = f2bf(gelu_f(acc[mi][ni][r] + bv));
                }
        }
    } else if (sg.mode == 2) {
#pragma unroll
        for (int ni = 0; ni < NT; ++ni) {
            const int col = wcol0 + ni * 16 + row_l;
            const float bv = sg.bias[col];
#pragma unroll
            for (int mi = 0; mi < MT; ++mi)
#pragma unroll
                for (int r = 0; r < 4; ++r) {
                    const int row = m0 + wrow0 + mi * 16 + kq * 4 + r;
                    sg.C[(size_t)row * sg.ldc + col] = f2bf(gelu_x(acc[mi][ni][r] + bv));
                }
        }
    } else {
#pragma unroll
        for (int mi = 0; mi < MT; ++mi)
#pragma unroll
            for (int r = 0; r < 4; ++r) {
                float s = 0.f;
#pragma unroll
                for (int ni = 0; ni < NT; ++ni) {
                    const int col = wcol0 + ni * 16 + row_l;
                    s += sg.dotw[col] * gelu_f(acc[mi][ni][r] + sg.bias[col]);
                }
                s += __shfl_xor(s, 1); s += __shfl_xor(s, 2);
                s += __shfl_xor(s, 4); s += __shfl_xor(s, 8);
                if (row_l == 0)
                    atomicAdd(sg.acc + m0 + wrow0 + mi * 16 + kq * 4 + r, s);
            }
    }
}

__global__ __launch_bounds__(256)
void gemm_k(SegPack p) {
    __shared__ bfu LDS[32768];                    // 64 KiB
    gemm_body(p, blockIdx.x, blockIdx.y, gridDim.x, LDS);
}

// -------- merged launch: disc2-dot GEMM (bx=0) | info-l2 + entropy (bx=1)
// entropy now 2 threads/row (partial counts merged via LDS; integer counts
// identical -> bitwise-same results).
__global__ __launch_bounds__(256)
void big2ent_k(SegPack p, const bfu* __restrict__ A, const bfu* __restrict__ W,
               const float* __restrict__ bias, const float* __restrict__ part,
               float* out, int B) {
    __shared__ __align__(16) char smemc[65536];
    if (blockIdx.x == 0) {                        // disc2-dot gemm path
        gemm_body(p, 0, blockIdx.y, 1, (bfu*)smemc);
        return;
    }
    // ------------- ent path: BN=64 GEMM (K=256) + fused histogram entropy
    constexpr int BK = 64, MT = 2, NT = 4;
    float* smemf = (float*)smemc;
    bfu* As0 = (bfu*)smemf;                       // 128x64 bf16 = 16 KB
    bfu* Ws0 = (bfu*)smemf + 8192;
    bfu* As1 = (bfu*)smemf + 12288;
    bfu* Ws1 = (bfu*)smemf + 20480;
    float* ET = smemf;                            // 128 x 65 fp32 after K-loop
    int* CN = (int*)(smemc + 33280);              // 256 x 11 partial counts
    const int K = 256, lda = 256;
    const int t = threadIdx.x;
    const int wave = t >> 6, lane = t & 63;
    const int row_l = lane & 15, kq = lane >> 4;
    const int m0 = blockIdx.y * 128;
    const int wrow0 = wave * 32;
    f32x4 acc[MT][NT] = {};
    const int nkt = K / BK;

    const int r0 = t >> 3;
    const int cc = ((t & 7) ^ (r0 & 7)) << 3;
    const size_t strA = (size_t)32 * lda;
    const size_t strW = (size_t)32 * K;
    const bfu* pA[4];
    const bfu* pW[2];
#pragma unroll
    for (int i = 0; i < 4; ++i)
        pA[i] = A + (size_t)(m0 + r0) * lda + cc + i * strA;
#pragma unroll
    for (int i = 0; i < 2; ++i)
        pW[i] = W + (size_t)r0 * K + cc + i * strW;

    auto stage = [&](bfu* Ad, bfu* Wd) {
#pragma unroll
        for (int i = 0; i < 4; ++i)
            async16(pA[i], Ad + ((i * 256 + wave * 64) << 3));
#pragma unroll
        for (int i = 0; i < 2; ++i)
            async16(pW[i], Wd + ((i * 256 + wave * 64) << 3));
#pragma unroll
        for (int i = 0; i < 4; ++i) pA[i] += BK;
#pragma unroll
        for (int i = 0; i < 2; ++i) pW[i] += BK;
    };
    auto compute = [&](const bfu* Ab, const bfu* Wb) {
#pragma unroll
        for (int ks = 0; ks < 2; ++ks) {
            bf16x8 af[MT], bfr[NT];
#pragma unroll
            for (int mi = 0; mi < MT; ++mi) {
                const int rA = wrow0 + mi * 16 + row_l;
                af[mi] = *(const bf16x8*)(Ab + rA * BK + (((ks * 4 + kq) ^ (rA & 7)) << 3));
            }
#pragma unroll
            for (int ni = 0; ni < NT; ++ni) {
                const int rB = ni * 16 + row_l;
                bfr[ni] = *(const bf16x8*)(Wb + rB * BK + (((ks * 4 + kq) ^ (rB & 7)) << 3));
            }
#pragma unroll
            for (int mi = 0; mi < MT; ++mi)
#pragma unroll
                for (int ni = 0; ni < NT; ++ni)
                    acc[mi][ni] = __builtin_amdgcn_mfma_f32_16x16x32_bf16(af[mi], bfr[ni], acc[mi][ni], 0, 0, 0);
        }
    };

    stage(As0, Ws0);
    __syncthreads();
    for (int kt = 0; kt < nkt; kt += 2) {
        stage(As1, Ws1);
        compute(As0, Ws0);
        __syncthreads();
        if (kt + 2 < nkt) stage(As0, Ws0);
        compute(As1, Ws1);
        __syncthreads();
    }

    // dump 128x64 fp32 logits (no activation) to LDS
#pragma unroll
    for (int mi = 0; mi < MT; ++mi)
#pragma unroll
        for (int ni = 0; ni < NT; ++ni) {
            const int col = ni * 16 + row_l;
            const float bv = bias[col];
#pragma unroll
            for (int r = 0; r < 4; ++r)
                ET[(wrow0 + mi * 16 + kq * 4 + r) * 65 + col] = acc[mi][ni][r] + bv;
        }
    __syncthreads();
    {   // 2 threads/row: each counts 32 logits, merge, entropy on t<128
        const int row = t & 127, hf = t >> 7;
        int cnt[11];
#pragma unroll
        for (int b = 0; b < 11; ++b) cnt[b] = 0;
        for (int j = hf * 32; j < hf * 32 + 32; ++j) {
            const int d = (int)rintf(sigm(ET[row * 65 + j]) * 10.f);
#pragma unroll
            for (int b = 0; b < 11; ++b) cnt[b] += (d == b);
        }
#pragma unroll
        for (int b = 0; b < 11; ++b) CN[t * 11 + b] = cnt[b];
    }
    __syncthreads();
    if (t < 128) {
        float ent = 0.f;
#pragma unroll
        for (int b = 0; b < 11; ++b) {
            const int c = CN[t * 11 + b] + CN[(t + 128) * 11 + b];
            if (c > 0) {
                const float pp = (float)c * (1.f / 64.f);
                ent -= pp * __logf(pp + 1e-8f);
            }
        }
        const int row = m0 + t;
        const int orow = (row < B) ? 4 : 5;
        const int rl = (row < B) ? row : row - B;
        out[(size_t)orow * B + rl] = part[row] + sigm(ent - 2.f) * (1.f / 3.f);
    }
}

// --------------- finalize: sigmoids over fused-dot accumulators + overall
__global__ __launch_bounds__(256)
void finalize_k(float* out, const float* a_imp1, const float* a_imp2,
                const float* a_co, const float* a_ce, const float* a_df,
                const float* a_d1, const float* a_d2,
                const float* imp_b2, const float* disc_b3,
                const float* cons_b3, const float* diff_b3, int B) {
    const int i = blockIdx.x * 256 + threadIdx.x;
    if (i >= B) return;
    const float ib = imp_b2[0], db = disc_b3[0], cb = cons_b3[0], fb = diff_b3[0];
    const float o6 = sigm(a_co[i] + cb);
    const float o7 = sigm(a_ce[i] + cb);
    const float o8 = sigm(a_imp1[i] + ib);
    const float o9 = sigm(a_imp1[B + i] + ib);
    out[6 * B + i] = o6;
    out[7 * B + i] = o7;
    out[8 * B + i] = o8;
    out[9 * B + i] = o9;
    out[10 * B + i] = sigm(a_imp2[i] + ib);
    out[11 * B + i] = sigm(a_imp2[B + i] + ib);
    out[12 * B + i] = sigm(a_d1[i] + db);
    out[14 * B + i] = sigm(a_d1[B + i] + db);
    out[13 * B + i] = sigm(a_d2[i] + db);
    out[15 * B + i] = sigm(a_d2[B + i] + db);
    out[16 * B + i] = sigm(a_df[i] + fb);
    const float v = out[0 * B + i] + out[1 * B + i] + out[4 * B + i] + out[5 * B + i] +
                    o7 + 0.5f * (o8 + o9);
    out[17 * B + i] = v * (1.f / 6.f);
}

extern "C" void kernel_launch(void* const* d_in, const int* in_sizes, int n_in,
                              void* d_out, int out_size, void* d_ws, size_t ws_size,
                              hipStream_t stream) {
    const int B = in_sizes[4];  // 16384
    const int B2 = 2 * B;
    float* out = (float*)d_out;
    const float* img  = (const float*)d_in[0];
    const float* txt  = (const float*)d_in[1];
    const float* eimg = (const float*)d_in[2];
    const float* etxt = (const float*)d_in[3];
    const float* info_w1 = (const float*)d_in[5];  const float* info_b1 = (const float*)d_in[6];
    const float* info_w2 = (const float*)d_in[7];  const float* info_b2 = (const float*)d_in[8];
    const float* imp_w1  = (const float*)d_in[9];  const float* imp_b1  = (const float*)d_in[10];
    const float* imp_w2  = (const float*)d_in[11]; const float* imp_b2  = (const float*)d_in[12];
    const float* disc_w1 = (const float*)d_in[13]; const float* disc_b1 = (const float*)d_in[14];
    const float* disc_w2 = (const float*)d_in[15]; const float* disc_b2 = (const float*)d_in[16];
    const float* disc_w3 = (const float*)d_in[17]; const float* disc_b3 = (const float*)d_in[18];
    const float* cons_w1 = (const float*)d_in[19]; const float* cons_b1 = (const float*)d_in[20];
    const float* cons_w2 = (const float*)d_in[21]; const float* cons_b2 = (const float*)d_in[22];
    const float* cons_w3 = (const float*)d_in[23]; const float* cons_b3 = (const float*)d_in[24];
    const float* diff_w1 = (const float*)d_in[25]; const float* diff_b1 = (const float*)d_in[26];
    const float* diff_w2 = (const float*)d_in[27]; const float* diff_b2 = (const float*)d_in[28];
    const float* diff_w3 = (const float*)d_in[29]; const float* diff_b3 = (const float*)d_in[30];

    char* wsp = (char*)d_ws;
    size_t off = 0;
    auto alloc = [&](size_t bytes) -> void* {
        void* p = wsp + off;
        off += (bytes + 255) & ~(size_t)255;
        return p;
    };
    // bf16 transposed weights [N][K]; disc2 padded to 128 N-rows
    bfu* info1t = (bfu*)alloc((size_t)256 * 768 * 2);
    bfu* info2t = (bfu*)alloc((size_t)64 * 256 * 2);
    bfu* imp1t  = (bfu*)alloc((size_t)384 * 768 * 2);
    bfu* disc1t = (bfu*)alloc((size_t)256 * 768 * 2);
    bfu* disc2p = (bfu*)alloc((size_t)128 * 256 * 2);   // rows 64-127 zeroed
    bfu* cons1t = (bfu*)alloc((size_t)768 * 1536 * 2);
    bfu* cons2t = (bfu*)alloc((size_t)384 * 768 * 2);
    bfu* diff1t = (bfu*)alloc((size_t)768 * 1536 * 2);
    bfu* diff2t = (bfu*)alloc((size_t)384 * 768 * 2);
    float* w3pad = (float*)alloc(128 * 4);
    float* b2pad = (float*)alloc(128 * 4);
    float* part = (float*)alloc((size_t)B2 * 4);
    // zeroed accumulators: imp1 2B | imp2 2B | co B | ce B | df B | d1 2B | d2 2B
    float* accz = (float*)alloc((size_t)11 * B * 4);
    float* a_imp1 = accz;
    float* a_imp2 = accz + B2;
    float* a_co = accz + 2 * B2;
    float* a_ce = a_co + B;
    float* a_df = a_ce + B;
    float* a_d1 = a_df + B;
    float* a_d2 = a_d1 + B2;
    bfu* fA01 = (bfu*)alloc((size_t)B2 * 768 * 2);      // 50.3 MB ph1 features
    bfu* X    = (bfu*)alloc((size_t)B * 2048 * 2);      // 67.1 MB hidden
    bfu* Hd   = X;                                      // [2B x 256]
    bfu* Hi   = X + (size_t)B * 512;                    // [2B x 256] (ph1 only)
    bfu* HcA  = X + (size_t)B * 1024;                   // ph1 cons1 out [B x 768]
    bfu* HcB  = X + (size_t)B * 512;                    // ph2 cons1 out (Hi dead)
    bfu* HcC  = X + (size_t)B * 1280;                   // ph2 diff1 out (HcA dead)
    // optional separate ph2 feature buffer -> geomcast ph2 joins setup launch
    const size_t fA2_bytes = (size_t)B2 * 768 * 2;
    bfu* fA2 = (bfu*)(wsp + off);
    const bool bigws = (off + fA2_bytes) <= ws_size;
    if (bigws) off += (fA2_bytes + 255) & ~(size_t)255;
    const bfu* fph2  = bigws ? fA2 : fA01;              // ph2 A base
    const bfu* fph2B = fph2 + (size_t)B * 768;
    (void)n_in; (void)out_size;

    // ---------------- launch 1: setup (transpose + prep + geomcast) ------
    SetupPack sp{};
    int blk = 0, ti = 0;
    auto setd = [&](const float* s, bfu* d, int K, int N) {
        sp.tp.d[ti++] = {s, d, K, N, blk};
        blk += (K / 64) * (N / 64);
    };
    setd(info_w1, info1t, 768, 256);
    setd(info_w2, info2t, 256, 64);
    setd(imp_w1, imp1t, 768, 384);
    setd(disc_w1, disc1t, 768, 256);
    setd(disc_w2, disc2p, 256, 64);                     // rows 0-63 of padded
    setd(cons_w1, cons1t, 1536, 768);
    setd(cons_w2, cons2t, 768, 384);
    setd(diff_w1, diff1t, 1536, 768);
    setd(diff_w2, diff2t, 768, 384);
    sp.nT = blk;                                        // 896
    sp.nP = (11 * B + 255) / 256;
    sp.Bq = B / 4;
    sp.accz = accz; sp.nacc = 11 * B; sp.disc2pad = disc2p;
    sp.w3f = disc_w3; sp.b2f = disc_b2; sp.w3pad = w3pad; sp.b2pad = b2pad;
    sp.g[0] = {img, fA01, out + 0 * B, part};
    sp.g[1] = {txt, fA01 + (size_t)B * 768, out + 1 * B, part + B};
    sp.g[2] = {eimg, fA2, out + 2 * B, nullptr};
    sp.g[3] = {etxt, fA2 + (size_t)B * 768, out + 3 * B, nullptr};
    sp.ng = bigws ? 4 : 2;
    setup_k<<<dim3(sp.nT + sp.nP + sp.ng * sp.Bq), 256, 0, stream>>>(sp);

    auto st_seg = [&](const bfu* A, const bfu* A2, const bfu* W, const float* b,
                      bfu* C, int ldc, int mode, int K, int Ksplit, int lda, int Mt) -> Seg {
        return Seg{A, A2, W, b, nullptr, C, nullptr, ldc, mode, K, Ksplit, lda, Mt};
    };
    auto dt_seg = [&](const bfu* A, const bfu* W, const float* b, const float* dw,
                      float* acc, int K, int lda, int Mt) -> Seg {
        return Seg{A, nullptr, W, b, dw, nullptr, acc, 0, 1, K, K, lda, Mt};
    };
    const bfu* fB = fA01 + (size_t)B * 768;
    const int MT2 = B2 / 128, MT1 = B / 128;            // 256 / 128 m-tiles

    // ------ launch 2: BIG1' = ph1 {info1 x2 | imp1-dot x3 | disc1 x2} +
    //                  ph1 cons1 x6 (K=1536 concat) — balanced vs BIG4 ------
    {
        SegPack p{};
        p.s[0] = st_seg(fA01, nullptr, info1t, info_b1, Hi, 256, 2, 768, 768, 768, MT2);
        p.s[1] = st_seg(fA01, nullptr, info1t + (size_t)128 * 768, info_b1 + 128, Hi + 128, 256, 2, 768, 768, 768, MT2);
        for (int i = 0; i < 3; ++i)
            p.s[2 + i] = dt_seg(fA01, imp1t + (size_t)128 * i * 768, imp_b1 + 128 * i,
                                imp_w2 + 128 * i, a_imp1, 768, 768, MT2);
        p.s[5] = st_seg(fA01, nullptr, disc1t, disc_b1, Hd, 256, 0, 768, 768, 768, MT2);
        p.s[6] = st_seg(fA01, nullptr, disc1t + (size_t)128 * 768, disc_b1 + 128, Hd + 128, 256, 0, 768, 768, 768, MT2);
        for (int i = 0; i < 6; ++i)
            p.s[7 + i] = st_seg(fA01, fB, cons1t + (size_t)128 * i * 1536,
                                cons_b1 + 128 * i, HcA + 128 * i, 768, 0, 1536, 768, 768, MT1);
        gemm_k<<<dim3(13, MT2), 256, 0, stream>>>(p);
    }

    // ------ launch 3: disc2-dot (Hd ph1) + info-l2/entropy merged ------
    {
        SegPack p{};
        p.s[0] = dt_seg(Hd, disc2p, b2pad, w3pad, a_d1, 256, 256, MT2);
        big2ent_k<<<dim3(2, MT2), 256, 0, stream>>>(p, Hi, info2t, info_b2, part, out, B);
    }

    // fallback: ph2 geomcast as its own launch (overwrites fA01)
    if (!bigws)
        geomcast_k<<<dim3(B / 4, 2), 256, 0, stream>>>(eimg, etxt, fA01, (bfu*)fB,
                                                       out + 2 * B, out + 3 * B, nullptr, nullptr);

    // ------ launch 4: BIG3: imp1-dot x3 | disc1 x2 (ph2) | cons2-dot x3 ------
    {
        SegPack p{};
        for (int i = 0; i < 3; ++i)
            p.s[i] = dt_seg(fph2, imp1t + (size_t)128 * i * 768, imp_b1 + 128 * i,
                            imp_w2 + 128 * i, a_imp2, 768, 768, MT2);
        p.s[3] = st_seg(fph2, nullptr, disc1t, disc_b1, Hd, 256, 0, 768, 768, 768, MT2);
        p.s[4] = st_seg(fph2, nullptr, disc1t + (size_t)128 * 768, disc_b1 + 128, Hd + 128, 256, 0, 768, 768, 768, MT2);
        for (int i = 0; i < 3; ++i)
            p.s[5 + i] = dt_seg(HcA, cons2t + (size_t)128 * i * 768, cons_b2 + 128 * i,
                                cons_w3 + 128 * i, a_co, 768, 768, MT1);
        gemm_k<<<dim3(8, MT2), 256, 0, stream>>>(p);
    }
    // ------ launch 5: BIG4: disc2-dot (ph2) | cons1 x6 | diff1 x6 ------
    {
        SegPack p{};
        p.s[0] = dt_seg(Hd, disc2p, b2pad, w3pad, a_d2, 256, 256, MT2);
        for (int i = 0; i < 6; ++i) {
            p.s[1 + i] = st_seg(fph2, fph2B, cons1t + (size_t)128 * i * 1536,
                                cons_b1 + 128 * i, HcB + 128 * i, 768, 0, 1536, 768, 768, MT1);
            p.s[7 + i] = st_seg(fph2, fph2B, diff1t + (size_t)128 * i * 1536,
                                diff_b1 + 128 * i, HcC + 128 * i, 768, 0, 1536, 768, 768, MT1);
        }
        gemm_k<<<dim3(13, MT2), 256, 0, stream>>>(p);
    }
    // ------ launch 6: BIG5: cons2-dot x3 | diff2-dot x3 ------
    {
        SegPack p{};
        for (int i = 0; i < 3; ++i) {
            p.s[i]     = dt_seg(HcB, cons2t + (size_t)128 * i * 768, cons_b2 + 128 * i,
                                cons_w3 + 128 * i, a_ce, 768, 768, MT1);
            p.s[3 + i] = dt_seg(HcC, diff2t + (size_t)128 * i * 768, diff_b2 + 128 * i,
                                diff_w3 + 128 * i, a_df, 768, 768, MT1);
        }
        gemm_k<<<dim3(6, MT1), 256, 0, stream>>>(p);
    }

    // ------ launch 7: finalize ------
    finalize_k<<<dim3((B + 255) / 256), 256, 0, stream>>>(out, a_imp1, a_imp2, a_co, a_ce,
                                                          a_df, a_d1, a_d2,
                                                          imp_b2, disc_b3, cons_b3, diff_b3, B);
}